// Round 1
// baseline (152.485 us; speedup 1.0000x reference)
//
#include <hip/hip_runtime.h>

#define B_  64
#define L_  512
#define D_  768
#define S_  64
#define M_  (B_ * S_)   // 4096 output rows
#define N1_ 384
#define N2_ 128

// ---------------------------------------------------------------------------
// Kernel 1: per-sample segment SUMS. seg_ids are sorted per sample, so each
// segment is a contiguous run of tokens. Accumulate the run in a register and
// flush with one atomicAdd per run (runs straddling L-chunk boundaries merge
// via the atomic). Grid: (D/256, L_CHUNKS, B), block 256.
// ---------------------------------------------------------------------------
__global__ __launch_bounds__(256) void seg_sum_kernel(
    const float* __restrict__ hidden, const int* __restrict__ seg_ids,
    float* __restrict__ sums) {
  const int LPC = 128;  // tokens per L-chunk (512/4)
  const int tid = threadIdx.x;
  const int d  = blockIdx.x * 256 + tid;   // 0..767
  const int lc = blockIdx.y;               // 0..3
  const int b  = blockIdx.z;

  __shared__ int sid[128];
  if (tid < LPC) sid[tid] = seg_ids[b * L_ + lc * LPC + tid];
  __syncthreads();

  const float* hp = hidden + ((size_t)b * L_ + (size_t)lc * LPC) * D_ + d;
  float racc = 0.0f;
  int cs = sid[0];
  #pragma unroll 8
  for (int l = 0; l < LPC; ++l) {
    int s = sid[l];               // wave-uniform
    if (s != cs) {                // uniform branch: run boundary
      atomicAdd(&sums[((size_t)b * S_ + cs) * D_ + d], racc);
      racc = 0.0f;
      cs = s;
    }
    racc += hp[(size_t)l * D_];
  }
  atomicAdd(&sums[((size_t)b * S_ + cs) * D_ + d], racc);
}

// ---------------------------------------------------------------------------
// Kernel 2: inverse counts per (b, s). Grid B, block 64 (1 wave).
// ---------------------------------------------------------------------------
__global__ __launch_bounds__(64) void cnt_kernel(
    const int* __restrict__ seg_ids, float* __restrict__ inv_cnt) {
  const int b = blockIdx.x;
  const int s = threadIdx.x;   // 0..63
  __shared__ int sid[L_];
  for (int l = s; l < L_; l += 64) sid[l] = seg_ids[b * L_ + l];
  __syncthreads();
  int c = 0;
  for (int l = 0; l < L_; ++l) c += (sid[l] == s) ? 1 : 0;
  inv_cnt[b * S_ + s] = 1.0f / (float)max(c, 1);
}

// ---------------------------------------------------------------------------
// Kernel 3: fp32 tiled GEMM  C = act(scale(A) * B + bias).
// A: [M,K] row-major (optionally row-scaled by rowscale[m]), B: [K,N], C: [M,N].
// BM=BN=64, BK=16, 256 threads, 4x4 per thread. M,N,K all divisible by tiles.
// ---------------------------------------------------------------------------
template <bool RELU>
__global__ __launch_bounds__(256) void gemm_kernel(
    const float* __restrict__ A, const float* __restrict__ Bm,
    const float* __restrict__ bias, const float* __restrict__ rowscale,
    float* __restrict__ C, int M, int N, int K) {
  constexpr int BM = 64, BN = 64, BK = 16;
  constexpr int LDA = BM + 4;  // pad to 68: keeps float4 alignment, breaks conflicts
  constexpr int LDB = BN + 4;
  __shared__ float As[BK][LDA];
  __shared__ float Bs[BK][LDB];

  const int tid  = threadIdx.x;
  const int brow = blockIdx.y * BM;
  const int bcol = blockIdx.x * BN;
  const int tr = (tid >> 4) << 2;   // 0..60 step 4 (m)
  const int tc = (tid & 15) << 2;   // 0..60 step 4 (n)

  // A-tile load mapping: 64 rows x 16 k, one float4 along K per thread
  const int arow = tid >> 2;          // 0..63
  const int ak   = (tid & 3) << 2;    // 0,4,8,12
  // B-tile load mapping: 16 k x 64 n, one float4 along N per thread
  const int bk = tid >> 4;            // 0..15
  const int bn = (tid & 15) << 2;     // 0..60

  const float ascale = rowscale ? rowscale[brow + arow] : 1.0f;

  float acc[4][4] = {};

  for (int kt = 0; kt < K; kt += BK) {
    float4 av = *(const float4*)(A + (size_t)(brow + arow) * K + kt + ak);
    float4 bv = *(const float4*)(Bm + (size_t)(kt + bk) * N + bcol + bn);
    __syncthreads();
    As[ak + 0][arow] = av.x * ascale;
    As[ak + 1][arow] = av.y * ascale;
    As[ak + 2][arow] = av.z * ascale;
    As[ak + 3][arow] = av.w * ascale;
    *(float4*)&Bs[bk][bn] = bv;
    __syncthreads();
    #pragma unroll
    for (int kk = 0; kk < BK; ++kk) {
      float4 a4 = *(const float4*)&As[kk][tr];
      float4 b4 = *(const float4*)&Bs[kk][tc];
      acc[0][0] += a4.x * b4.x; acc[0][1] += a4.x * b4.y;
      acc[0][2] += a4.x * b4.z; acc[0][3] += a4.x * b4.w;
      acc[1][0] += a4.y * b4.x; acc[1][1] += a4.y * b4.y;
      acc[1][2] += a4.y * b4.z; acc[1][3] += a4.y * b4.w;
      acc[2][0] += a4.z * b4.x; acc[2][1] += a4.z * b4.y;
      acc[2][2] += a4.z * b4.z; acc[2][3] += a4.z * b4.w;
      acc[3][0] += a4.w * b4.x; acc[3][1] += a4.w * b4.y;
      acc[3][2] += a4.w * b4.z; acc[3][3] += a4.w * b4.w;
    }
  }

  #pragma unroll
  for (int i = 0; i < 4; ++i) {
    float4 o;
    o.x = acc[i][0] + bias[bcol + tc + 0];
    o.y = acc[i][1] + bias[bcol + tc + 1];
    o.z = acc[i][2] + bias[bcol + tc + 2];
    o.w = acc[i][3] + bias[bcol + tc + 3];
    if (RELU) {
      o.x = fmaxf(o.x, 0.0f); o.y = fmaxf(o.y, 0.0f);
      o.z = fmaxf(o.z, 0.0f); o.w = fmaxf(o.w, 0.0f);
    }
    *(float4*)&C[(size_t)(brow + tr + i) * N + bcol + tc] = o;
  }
}

// ---------------------------------------------------------------------------
// Kernel 4: logits = h2 @ W3 + b3, N=2. One thread per output row.
// ---------------------------------------------------------------------------
__global__ __launch_bounds__(256) void final_kernel(
    const float* __restrict__ h2, const float* __restrict__ W3,
    const float* __restrict__ b3, float* __restrict__ out) {
  __shared__ float w[N2_ * 2];
  const int tid = threadIdx.x;
  w[tid] = W3[tid];  // 256 elements exactly
  __syncthreads();
  const int m = blockIdx.x * 256 + tid;
  float a0 = b3[0], a1 = b3[1];
  const float* hp = h2 + (size_t)m * N2_;
  #pragma unroll
  for (int k = 0; k < N2_; k += 4) {
    float4 v = *(const float4*)(hp + k);
    a0 += v.x * w[(k + 0) * 2]; a1 += v.x * w[(k + 0) * 2 + 1];
    a0 += v.y * w[(k + 1) * 2]; a1 += v.y * w[(k + 1) * 2 + 1];
    a0 += v.z * w[(k + 2) * 2]; a1 += v.z * w[(k + 2) * 2 + 1];
    a0 += v.w * w[(k + 3) * 2]; a1 += v.w * w[(k + 3) * 2 + 1];
  }
  out[(size_t)m * 2 + 0] = a0;
  out[(size_t)m * 2 + 1] = a1;
}

// ---------------------------------------------------------------------------
extern "C" void kernel_launch(void* const* d_in, const int* in_sizes, int n_in,
                              void* d_out, int out_size, void* d_ws, size_t ws_size,
                              hipStream_t stream) {
  const float* hidden  = (const float*)d_in[0];
  const int*   seg_ids = (const int*)d_in[1];
  const float* W1 = (const float*)d_in[2];
  const float* b1 = (const float*)d_in[3];
  const float* W2 = (const float*)d_in[4];
  const float* b2 = (const float*)d_in[5];
  const float* W3 = (const float*)d_in[6];
  const float* b3 = (const float*)d_in[7];
  float* out = (float*)d_out;

  float* sums = (float*)d_ws;                  // [4096, 768]
  float* h1   = sums + (size_t)M_ * D_;        // [4096, 384]
  float* h2   = h1 + (size_t)M_ * N1_;         // [4096, 128]
  float* inv  = h2 + (size_t)M_ * N2_;         // [4096]

  // sums accumulates via atomics -> must be zeroed every call
  hipMemsetAsync(sums, 0, (size_t)M_ * D_ * sizeof(float), stream);

  seg_sum_kernel<<<dim3(3, 4, B_), 256, 0, stream>>>(hidden, seg_ids, sums);
  cnt_kernel<<<B_, 64, 0, stream>>>(seg_ids, inv);
  gemm_kernel<true><<<dim3(N1_ / 64, M_ / 64), 256, 0, stream>>>(
      sums, W1, b1, inv, h1, M_, N1_, D_);
  gemm_kernel<true><<<dim3(N2_ / 64, M_ / 64), 256, 0, stream>>>(
      h1, W2, b2, nullptr, h2, M_, N2_, N1_);
  final_kernel<<<M_ / 256, 256, 0, stream>>>(h2, W3, b3, out);
}

// Round 2
// 122.088 us; speedup vs baseline: 1.2490x; 1.2490x over previous
//
#include <hip/hip_runtime.h>

#define B_  64
#define L_  512
#define D_  768
#define S_  64
#define M_  (B_ * S_)   // 4096 output rows
#define N1_ 384
#define N2_ 128

// ---------------------------------------------------------------------------
// Kernel 1: per-(b,s) segment bounds. seg_ids sorted per sample, so
// start[s] = #tokens < s, cnt[s] = #tokens == s. One wave per sample.
// ---------------------------------------------------------------------------
__global__ __launch_bounds__(64) void bounds_kernel(
    const int* __restrict__ seg_ids, int* __restrict__ starts,
    int* __restrict__ cnts) {
  const int b = blockIdx.x;
  const int s = threadIdx.x;   // 0..63
  __shared__ int sid[L_];
  for (int l = s; l < L_; l += 64) sid[l] = seg_ids[b * L_ + l];
  __syncthreads();
  int st = 0, c = 0;
  #pragma unroll 8
  for (int l = 0; l < L_; ++l) {
    int v = sid[l];
    st += (v < s) ? 1 : 0;
    c  += (v == s) ? 1 : 0;
  }
  starts[b * S_ + s] = st;
  cnts[b * S_ + s]   = c;
}

// ---------------------------------------------------------------------------
// Kernel 2: direct segment MEAN. One block per (s, b); 192 threads, each owns
// one float4 column (192*4 = 768 = D). Loop over the segment's contiguous
// token run; fully coalesced 3 KB row reads; no atomics. Mean division fused.
// ---------------------------------------------------------------------------
__global__ __launch_bounds__(192) void seg_mean_kernel(
    const float* __restrict__ hidden, const int* __restrict__ starts,
    const int* __restrict__ cnts, float* __restrict__ means) {
  const int s = blockIdx.x;
  const int b = blockIdx.y;
  const int st = starts[b * S_ + s];
  const int c  = cnts[b * S_ + s];
  const int t  = threadIdx.x;  // 0..191

  const float4* hp = (const float4*)(hidden + ((size_t)b * L_ + st) * D_) + t;
  float4 acc = {0.0f, 0.0f, 0.0f, 0.0f};
  #pragma unroll 4
  for (int l = 0; l < c; ++l) {
    float4 v = hp[(size_t)l * (D_ / 4)];
    acc.x += v.x; acc.y += v.y; acc.z += v.z; acc.w += v.w;
  }
  const float inv = 1.0f / (float)max(c, 1);
  float4 o = {acc.x * inv, acc.y * inv, acc.z * inv, acc.w * inv};
  ((float4*)(means + ((size_t)b * S_ + s) * D_))[t] = o;
}

// ---------------------------------------------------------------------------
// Kernel 3: fp32 tiled GEMM  C = act(A * B + bias).
// A: [M,K] row-major, B: [K,N], C: [M,N].
// BM=BN=64, BK=16, 256 threads, 4x4 per thread. M,N,K all divisible by tiles.
// ---------------------------------------------------------------------------
template <bool RELU>
__global__ __launch_bounds__(256) void gemm_kernel(
    const float* __restrict__ A, const float* __restrict__ Bm,
    const float* __restrict__ bias, float* __restrict__ C,
    int M, int N, int K) {
  constexpr int BM = 64, BN = 64, BK = 16;
  constexpr int LDA = BM + 4;
  constexpr int LDB = BN + 4;
  __shared__ float As[BK][LDA];
  __shared__ float Bs[BK][LDB];

  const int tid  = threadIdx.x;
  const int brow = blockIdx.y * BM;
  const int bcol = blockIdx.x * BN;
  const int tr = (tid >> 4) << 2;   // m
  const int tc = (tid & 15) << 2;   // n

  const int arow = tid >> 2;          // 0..63
  const int ak   = (tid & 3) << 2;    // 0,4,8,12
  const int bk = tid >> 4;            // 0..15
  const int bn = (tid & 15) << 2;     // 0..60

  float acc[4][4] = {};

  for (int kt = 0; kt < K; kt += BK) {
    float4 av = *(const float4*)(A + (size_t)(brow + arow) * K + kt + ak);
    float4 bv = *(const float4*)(Bm + (size_t)(kt + bk) * N + bcol + bn);
    __syncthreads();
    As[ak + 0][arow] = av.x;
    As[ak + 1][arow] = av.y;
    As[ak + 2][arow] = av.z;
    As[ak + 3][arow] = av.w;
    *(float4*)&Bs[bk][bn] = bv;
    __syncthreads();
    #pragma unroll
    for (int kk = 0; kk < BK; ++kk) {
      float4 a4 = *(const float4*)&As[kk][tr];
      float4 b4 = *(const float4*)&Bs[kk][tc];
      acc[0][0] += a4.x * b4.x; acc[0][1] += a4.x * b4.y;
      acc[0][2] += a4.x * b4.z; acc[0][3] += a4.x * b4.w;
      acc[1][0] += a4.y * b4.x; acc[1][1] += a4.y * b4.y;
      acc[1][2] += a4.y * b4.z; acc[1][3] += a4.y * b4.w;
      acc[2][0] += a4.z * b4.x; acc[2][1] += a4.z * b4.y;
      acc[2][2] += a4.z * b4.z; acc[2][3] += a4.z * b4.w;
      acc[3][0] += a4.w * b4.x; acc[3][1] += a4.w * b4.y;
      acc[3][2] += a4.w * b4.z; acc[3][3] += a4.w * b4.w;
    }
  }

  #pragma unroll
  for (int i = 0; i < 4; ++i) {
    float4 o;
    o.x = acc[i][0] + bias[bcol + tc + 0];
    o.y = acc[i][1] + bias[bcol + tc + 1];
    o.z = acc[i][2] + bias[bcol + tc + 2];
    o.w = acc[i][3] + bias[bcol + tc + 3];
    if (RELU) {
      o.x = fmaxf(o.x, 0.0f); o.y = fmaxf(o.y, 0.0f);
      o.z = fmaxf(o.z, 0.0f); o.w = fmaxf(o.w, 0.0f);
    }
    *(float4*)&C[(size_t)(brow + tr + i) * N + bcol + tc] = o;
  }
}

// ---------------------------------------------------------------------------
// Kernel 4: logits = h2 @ W3 + b3, N=2. One thread per output row.
// ---------------------------------------------------------------------------
__global__ __launch_bounds__(256) void final_kernel(
    const float* __restrict__ h2, const float* __restrict__ W3,
    const float* __restrict__ b3, float* __restrict__ out) {
  __shared__ float w[N2_ * 2];
  const int tid = threadIdx.x;
  w[tid] = W3[tid];  // 256 elements exactly
  __syncthreads();
  const int m = blockIdx.x * 256 + tid;
  float a0 = b3[0], a1 = b3[1];
  const float* hp = h2 + (size_t)m * N2_;
  #pragma unroll
  for (int k = 0; k < N2_; k += 4) {
    float4 v = *(const float4*)(hp + k);
    a0 += v.x * w[(k + 0) * 2]; a1 += v.x * w[(k + 0) * 2 + 1];
    a0 += v.y * w[(k + 1) * 2]; a1 += v.y * w[(k + 1) * 2 + 1];
    a0 += v.z * w[(k + 2) * 2]; a1 += v.z * w[(k + 2) * 2 + 1];
    a0 += v.w * w[(k + 3) * 2]; a1 += v.w * w[(k + 3) * 2 + 1];
  }
  out[(size_t)m * 2 + 0] = a0;
  out[(size_t)m * 2 + 1] = a1;
}

// ---------------------------------------------------------------------------
extern "C" void kernel_launch(void* const* d_in, const int* in_sizes, int n_in,
                              void* d_out, int out_size, void* d_ws, size_t ws_size,
                              hipStream_t stream) {
  const float* hidden  = (const float*)d_in[0];
  const int*   seg_ids = (const int*)d_in[1];
  const float* W1 = (const float*)d_in[2];
  const float* b1 = (const float*)d_in[3];
  const float* W2 = (const float*)d_in[4];
  const float* b2 = (const float*)d_in[5];
  const float* W3 = (const float*)d_in[6];
  const float* b3 = (const float*)d_in[7];
  float* out = (float*)d_out;

  float* means = (float*)d_ws;                    // [4096, 768]
  float* h1    = means + (size_t)M_ * D_;         // [4096, 384]
  float* h2    = h1 + (size_t)M_ * N1_;           // [4096, 128]
  int*   starts = (int*)(h2 + (size_t)M_ * N2_);  // [4096]
  int*   cnts   = starts + M_;                    // [4096]

  bounds_kernel<<<B_, 64, 0, stream>>>(seg_ids, starts, cnts);
  seg_mean_kernel<<<dim3(S_, B_), 192, 0, stream>>>(hidden, starts, cnts, means);
  gemm_kernel<true><<<dim3(N1_ / 64, M_ / 64), 256, 0, stream>>>(
      means, W1, b1, h1, M_, N1_, D_);
  gemm_kernel<true><<<dim3(N2_ / 64, M_ / 64), 256, 0, stream>>>(
      h1, W2, b2, h2, M_, N2_, N1_);
  final_kernel<<<M_ / 256, 256, 0, stream>>>(h2, W3, b3, out);
}

// Round 3
// 72.746 us; speedup vs baseline: 2.0961x; 1.6783x over previous
//
#include <hip/hip_runtime.h>

#define B_  64
#define L_  512
#define D_  768
#define S_  64
#define M_  (B_ * S_)   // 4096 output rows
#define N1_ 384
#define N2_ 128

typedef __attribute__((ext_vector_type(8))) short short8;
typedef __attribute__((ext_vector_type(4))) float f32x4;

__device__ __forceinline__ ushort f2bf(float x) {
  uint u = __float_as_uint(x);
  uint r = (u + 0x7fffu + ((u >> 16) & 1u)) >> 16;
  return (ushort)r;
}
__device__ __forceinline__ float bf2f(ushort h) {
  return __uint_as_float(((uint)h) << 16);
}

// ---------------------------------------------------------------------------
// Kernel 1: per-(b,s) segment bounds (seg_ids sorted per sample).
// ---------------------------------------------------------------------------
__global__ __launch_bounds__(64) void bounds_kernel(
    const int* __restrict__ seg_ids, int* __restrict__ starts,
    int* __restrict__ cnts) {
  const int b = blockIdx.x;
  const int s = threadIdx.x;   // 0..63
  __shared__ int sid[L_];
  for (int l = s; l < L_; l += 64) sid[l] = seg_ids[b * L_ + l];
  __syncthreads();
  int st = 0, c = 0;
  #pragma unroll 8
  for (int l = 0; l < L_; ++l) {
    int v = sid[l];
    st += (v < s) ? 1 : 0;
    c  += (v == s) ? 1 : 0;
  }
  starts[b * S_ + s] = st;
  cnts[b * S_ + s]   = c;
}

// ---------------------------------------------------------------------------
// Kernel 2: segment MEAN -> bf16 hi/lo split output [M, D].
// One block per (s, b); 192 threads, each owns one float4 column.
// ---------------------------------------------------------------------------
__global__ __launch_bounds__(192) void seg_mean_kernel(
    const float* __restrict__ hidden, const int* __restrict__ starts,
    const int* __restrict__ cnts, ushort* __restrict__ mh,
    ushort* __restrict__ ml) {
  const int s = blockIdx.x;
  const int b = blockIdx.y;
  const int st = starts[b * S_ + s];
  const int c  = cnts[b * S_ + s];
  const int t  = threadIdx.x;  // 0..191

  const float4* hp = (const float4*)(hidden + ((size_t)b * L_ + st) * D_) + t;
  float4 acc = {0.0f, 0.0f, 0.0f, 0.0f};
  #pragma unroll 4
  for (int l = 0; l < c; ++l) {
    float4 v = hp[(size_t)l * (D_ / 4)];
    acc.x += v.x; acc.y += v.y; acc.z += v.z; acc.w += v.w;
  }
  const float inv = 1.0f / (float)max(c, 1);
  float o[4] = {acc.x * inv, acc.y * inv, acc.z * inv, acc.w * inv};
  ushort4 h, l4;
  h.x = f2bf(o[0]); l4.x = f2bf(o[0] - bf2f(h.x));
  h.y = f2bf(o[1]); l4.y = f2bf(o[1] - bf2f(h.y));
  h.z = f2bf(o[2]); l4.z = f2bf(o[2] - bf2f(h.z));
  h.w = f2bf(o[3]); l4.w = f2bf(o[3] - bf2f(h.w));
  const size_t idx = ((size_t)b * S_ + s) * D_ + t * 4;
  *(ushort4*)&mh[idx] = h;
  *(ushort4*)&ml[idx] = l4;
}

// ---------------------------------------------------------------------------
// Kernel 3: weight transpose + bf16 hi/lo split. W [K][N] f32 -> WT_hi/lo
// [N][K] bf16. Grid (N/32, K/32), block (32, 8). LDS tile transpose.
// ---------------------------------------------------------------------------
__global__ __launch_bounds__(256) void wsplit_kernel(
    const float* __restrict__ W, ushort* __restrict__ Wth,
    ushort* __restrict__ Wtl, int K, int N) {
  __shared__ float tile[32][33];
  const int n0 = blockIdx.x * 32, k0 = blockIdx.y * 32;
  const int tx = threadIdx.x, ty = threadIdx.y;  // tx 0..31, ty 0..7
  #pragma unroll
  for (int r = 0; r < 32; r += 8)
    tile[ty + r][tx] = W[(size_t)(k0 + ty + r) * N + n0 + tx];
  __syncthreads();
  #pragma unroll
  for (int r = 0; r < 32; r += 8) {
    float x = tile[tx][ty + r];  // W[k0+tx][n0+ty+r]
    ushort h = f2bf(x);
    ushort l = f2bf(x - bf2f(h));
    Wth[(size_t)(n0 + ty + r) * K + k0 + tx] = h;
    Wtl[(size_t)(n0 + ty + r) * K + k0 + tx] = l;
  }
}

// ---------------------------------------------------------------------------
// Kernel 4: MFMA GEMM with bf16 hi/lo split (3-pass: hh + hl + lh).
// A: [M][K] bf16 hi/lo row-major. B: B^T layout [N][K] bf16 hi/lo.
// C = relu?(A@B + bias). WRITE_SPLIT: emit C as bf16 hi/lo, else fp32.
// 64x64 tile, 4 waves (2x2 of 32x32), mfma_f32_16x16x32_bf16 2x2 frags.
// Double-buffered LDS, early-issued global loads.
// ---------------------------------------------------------------------------
template <bool RELU, bool WRITE_SPLIT>
__global__ __launch_bounds__(256) void gemm_mfma(
    const ushort* __restrict__ Ah, const ushort* __restrict__ Al,
    const ushort* __restrict__ Bh, const ushort* __restrict__ Bl,
    const float* __restrict__ bias, float* __restrict__ Cf,
    ushort* __restrict__ Ch, ushort* __restrict__ Cl,
    int M, int N, int K) {
  constexpr int LDA = 40;  // padded row stride (elements) for [64][32] tiles
  __shared__ __align__(16) ushort lds[2][4][64 * LDA];  // Ah, Al, Bh, Bl

  const int tid  = threadIdx.x;
  const int wid  = tid >> 6;
  const int lane = tid & 63;
  const int m0 = (wid >> 1) * 32;
  const int n0 = (wid & 1) * 32;
  const int lrow = lane & 15;
  const int lk   = (lane >> 4) * 8;

  const int srow = tid >> 2;        // 0..63
  const int sk   = (tid & 3) * 8;   // 0,8,16,24

  const int brow = blockIdx.y * 64;
  const int bcol = blockIdx.x * 64;

  const ushort* Aph = Ah + (size_t)(brow + srow) * K + sk;
  const ushort* Apl = Al + (size_t)(brow + srow) * K + sk;
  const ushort* Bph = Bh + (size_t)(bcol + srow) * K + sk;
  const ushort* Bpl = Bl + (size_t)(bcol + srow) * K + sk;

  const int NT = K / 32;
  const int soff = srow * LDA + sk;

  uint4 ra_h = *(const uint4*)Aph;
  uint4 ra_l = *(const uint4*)Apl;
  uint4 rb_h = *(const uint4*)Bph;
  uint4 rb_l = *(const uint4*)Bpl;
  *(uint4*)&lds[0][0][soff] = ra_h;
  *(uint4*)&lds[0][1][soff] = ra_l;
  *(uint4*)&lds[0][2][soff] = rb_h;
  *(uint4*)&lds[0][3][soff] = rb_l;
  __syncthreads();

  f32x4 acc[2][2] = {};

  for (int t = 0; t < NT; ++t) {
    const int cur = t & 1;
    if (t + 1 < NT) {  // issue next-tile loads early (hide HBM under MFMA)
      ra_h = *(const uint4*)(Aph + (size_t)(t + 1) * 32);
      ra_l = *(const uint4*)(Apl + (size_t)(t + 1) * 32);
      rb_h = *(const uint4*)(Bph + (size_t)(t + 1) * 32);
      rb_l = *(const uint4*)(Bpl + (size_t)(t + 1) * 32);
    }
    short8 ah[2], al[2], bh[2], bl[2];
    #pragma unroll
    for (int i = 0; i < 2; ++i) {
      const int ro = (m0 + i * 16 + lrow) * LDA + lk;
      ah[i] = *(const short8*)&lds[cur][0][ro];
      al[i] = *(const short8*)&lds[cur][1][ro];
    }
    #pragma unroll
    for (int j = 0; j < 2; ++j) {
      const int ro = (n0 + j * 16 + lrow) * LDA + lk;
      bh[j] = *(const short8*)&lds[cur][2][ro];
      bl[j] = *(const short8*)&lds[cur][3][ro];
    }
    #pragma unroll
    for (int i = 0; i < 2; ++i)
      #pragma unroll
      for (int j = 0; j < 2; ++j) {
        acc[i][j] = __builtin_amdgcn_mfma_f32_16x16x32_bf16(ah[i], bh[j], acc[i][j], 0, 0, 0);
        acc[i][j] = __builtin_amdgcn_mfma_f32_16x16x32_bf16(ah[i], bl[j], acc[i][j], 0, 0, 0);
        acc[i][j] = __builtin_amdgcn_mfma_f32_16x16x32_bf16(al[i], bh[j], acc[i][j], 0, 0, 0);
      }
    if (t + 1 < NT) {
      __syncthreads();
      const int nxt = cur ^ 1;
      *(uint4*)&lds[nxt][0][soff] = ra_h;
      *(uint4*)&lds[nxt][1][soff] = ra_l;
      *(uint4*)&lds[nxt][2][soff] = rb_h;
      *(uint4*)&lds[nxt][3][soff] = rb_l;
      __syncthreads();
    }
  }

  // epilogue: bias + relu; C/D layout col=lane&15, row=(lane>>4)*4+r (m89)
  #pragma unroll
  for (int i = 0; i < 2; ++i)
    #pragma unroll
    for (int j = 0; j < 2; ++j) {
      const float bj = bias[bcol + n0 + j * 16 + lrow];
      #pragma unroll
      for (int r = 0; r < 4; ++r) {
        float v = acc[i][j][r] + bj;
        if (RELU) v = fmaxf(v, 0.0f);
        const size_t idx =
            (size_t)(brow + m0 + i * 16 + (lane >> 4) * 4 + r) * N +
            bcol + n0 + j * 16 + lrow;
        if (WRITE_SPLIT) {
          ushort h = f2bf(v);
          Ch[idx] = h;
          Cl[idx] = f2bf(v - bf2f(h));
        } else {
          Cf[idx] = v;
        }
      }
    }
}

// ---------------------------------------------------------------------------
// Kernel 5: logits = h2 @ W3 + b3, N=2. One thread per output row.
// ---------------------------------------------------------------------------
__global__ __launch_bounds__(256) void final_kernel(
    const float* __restrict__ h2, const float* __restrict__ W3,
    const float* __restrict__ b3, float* __restrict__ out) {
  __shared__ float w[N2_ * 2];
  const int tid = threadIdx.x;
  w[tid] = W3[tid];  // 256 elements exactly
  __syncthreads();
  const int m = blockIdx.x * 256 + tid;
  float a0 = b3[0], a1 = b3[1];
  const float* hp = h2 + (size_t)m * N2_;
  #pragma unroll
  for (int k = 0; k < N2_; k += 4) {
    float4 v = *(const float4*)(hp + k);
    a0 += v.x * w[(k + 0) * 2]; a1 += v.x * w[(k + 0) * 2 + 1];
    a0 += v.y * w[(k + 1) * 2]; a1 += v.y * w[(k + 1) * 2 + 1];
    a0 += v.z * w[(k + 2) * 2]; a1 += v.z * w[(k + 2) * 2 + 1];
    a0 += v.w * w[(k + 3) * 2]; a1 += v.w * w[(k + 3) * 2 + 1];
  }
  out[(size_t)m * 2 + 0] = a0;
  out[(size_t)m * 2 + 1] = a1;
}

// ---------------------------------------------------------------------------
extern "C" void kernel_launch(void* const* d_in, const int* in_sizes, int n_in,
                              void* d_out, int out_size, void* d_ws, size_t ws_size,
                              hipStream_t stream) {
  const float* hidden  = (const float*)d_in[0];
  const int*   seg_ids = (const int*)d_in[1];
  const float* W1 = (const float*)d_in[2];
  const float* b1 = (const float*)d_in[3];
  const float* W2 = (const float*)d_in[4];
  const float* b2 = (const float*)d_in[5];
  const float* W3 = (const float*)d_in[6];
  const float* b3 = (const float*)d_in[7];
  float* out = (float*)d_out;

  // workspace layout (all 16B-aligned)
  char* p = (char*)d_ws;
  ushort* mh   = (ushort*)p;  p += (size_t)M_ * D_ * 2;    // 6.29 MB
  ushort* ml   = (ushort*)p;  p += (size_t)M_ * D_ * 2;
  ushort* w1th = (ushort*)p;  p += (size_t)N1_ * D_ * 2;   // 0.59 MB
  ushort* w1tl = (ushort*)p;  p += (size_t)N1_ * D_ * 2;
  ushort* h1h  = (ushort*)p;  p += (size_t)M_ * N1_ * 2;   // 3.15 MB
  ushort* h1l  = (ushort*)p;  p += (size_t)M_ * N1_ * 2;
  ushort* w2th = (ushort*)p;  p += (size_t)N2_ * N1_ * 2;  // 98 KB
  ushort* w2tl = (ushort*)p;  p += (size_t)N2_ * N1_ * 2;
  float*  h2   = (float*)p;   p += (size_t)M_ * N2_ * 4;   // 2.1 MB
  int* starts  = (int*)p;     p += (size_t)M_ * 4;
  int* cnts    = (int*)p;

  bounds_kernel<<<B_, 64, 0, stream>>>(seg_ids, starts, cnts);
  seg_mean_kernel<<<dim3(S_, B_), 192, 0, stream>>>(hidden, starts, cnts, mh, ml);
  wsplit_kernel<<<dim3(N1_ / 32, D_ / 32), dim3(32, 8), 0, stream>>>(W1, w1th, w1tl, D_, N1_);
  wsplit_kernel<<<dim3(N2_ / 32, N1_ / 32), dim3(32, 8), 0, stream>>>(W2, w2th, w2tl, N1_, N2_);
  gemm_mfma<true, true><<<dim3(N1_ / 64, M_ / 64), 256, 0, stream>>>(
      mh, ml, w1th, w1tl, b1, nullptr, h1h, h1l, M_, N1_, D_);
  gemm_mfma<true, false><<<dim3(N2_ / 64, M_ / 64), 256, 0, stream>>>(
      h1h, h1l, w2th, w2tl, b2, h2, nullptr, nullptr, M_, N2_, N1_);
  final_kernel<<<M_ / 256, 256, 0, stream>>>(h2, W3, b3, out);
}

// Round 4
// 60.870 us; speedup vs baseline: 2.5051x; 1.1951x over previous
//
#include <hip/hip_runtime.h>

#define B_  64
#define L_  512
#define D_  768
#define S_  64
#define M_  (B_ * S_)   // 4096 output rows
#define N1_ 384
#define N2_ 128

typedef __attribute__((ext_vector_type(8))) short short8;
typedef __attribute__((ext_vector_type(4))) float f32x4;

__device__ __forceinline__ ushort f2bf(float x) {
  uint u = __float_as_uint(x);
  uint r = (u + 0x7fffu + ((u >> 16) & 1u)) >> 16;
  return (ushort)r;
}
__device__ __forceinline__ float bf2f(ushort h) {
  return __uint_as_float(((uint)h) << 16);
}
__device__ __forceinline__ float4 f4add(float4 a, float4 b) {
  return make_float4(a.x + b.x, a.y + b.y, a.z + b.z, a.w + b.w);
}

// ---------------------------------------------------------------------------
// Kernel 1 (merged prep): blocks 0..63 -> segment bounds per sample;
// blocks 64..351 -> W1 transpose+split; blocks 352..399 -> W2.
// ---------------------------------------------------------------------------
__global__ __launch_bounds__(256) void prep_kernel(
    const int* __restrict__ seg_ids, int* __restrict__ starts,
    int* __restrict__ cnts, const float* __restrict__ W1,
    ushort* __restrict__ w1th, ushort* __restrict__ w1tl,
    const float* __restrict__ W2, ushort* __restrict__ w2th,
    ushort* __restrict__ w2tl) {
  const int bid = blockIdx.x;
  const int tid = threadIdx.x;
  if (bid < B_) {
    // --- bounds: st[s] = #tokens < s, c[s] = #tokens == s (sorted ids) ---
    __shared__ int sid[L_];
    __shared__ int pst[4][64];
    __shared__ int pc[4][64];
    const int b = bid;
    sid[tid]       = seg_ids[b * L_ + tid];
    sid[tid + 256] = seg_ids[b * L_ + tid + 256];
    __syncthreads();
    const int s = tid & 63, prt = tid >> 6;
    int st = 0, c = 0;
    const int base = prt * 128;
    #pragma unroll 8
    for (int l = 0; l < 128; ++l) {
      int v = sid[base + l];
      st += (v < s) ? 1 : 0;
      c  += (v == s) ? 1 : 0;
    }
    pst[prt][s] = st;
    pc[prt][s]  = c;
    __syncthreads();
    if (tid < 64) {
      starts[b * S_ + tid] = pst[0][tid] + pst[1][tid] + pst[2][tid] + pst[3][tid];
      cnts[b * S_ + tid]   = pc[0][tid] + pc[1][tid] + pc[2][tid] + pc[3][tid];
    }
  } else {
    // --- weight transpose + hi/lo split ---
    int wb = bid - B_;
    const float* W; ushort *Wth, *Wtl; int K, N, nblk, kblk;
    if (wb < 288) {  // W1: (384/32)*(768/32) = 12*24
      W = W1; Wth = w1th; Wtl = w1tl; K = D_; N = N1_;
      nblk = wb % 12; kblk = wb / 12;
    } else {         // W2: (128/32)*(384/32) = 4*12
      wb -= 288;
      W = W2; Wth = w2th; Wtl = w2tl; K = N1_; N = N2_;
      nblk = wb % 4; kblk = wb / 4;
    }
    __shared__ float tile[32][33];
    const int n0 = nblk * 32, k0 = kblk * 32;
    const int tx = tid & 31, ty = tid >> 5;  // 32 x 8
    #pragma unroll
    for (int r = 0; r < 32; r += 8)
      tile[ty + r][tx] = W[(size_t)(k0 + ty + r) * N + n0 + tx];
    __syncthreads();
    #pragma unroll
    for (int r = 0; r < 32; r += 8) {
      float x = tile[tx][ty + r];  // W[k0+tx][n0+ty+r]
      ushort h = f2bf(x);
      ushort lo = f2bf(x - bf2f(h));
      Wth[(size_t)(n0 + ty + r) * K + k0 + tx] = h;
      Wtl[(size_t)(n0 + ty + r) * K + k0 + tx] = lo;
    }
  }
}

// ---------------------------------------------------------------------------
// Kernel 2: segment MEAN -> bf16 hi/lo [M, D]. One block per (s, b);
// 192 threads each own one float4 column. 8 loads in flight + 4 independent
// accumulators to cover HBM latency (segments avg 8 tokens).
// ---------------------------------------------------------------------------
__global__ __launch_bounds__(192) void seg_mean_kernel(
    const float* __restrict__ hidden, const int* __restrict__ starts,
    const int* __restrict__ cnts, ushort* __restrict__ mh,
    ushort* __restrict__ ml) {
  const int s = blockIdx.x;
  const int b = blockIdx.y;
  const int st = starts[b * S_ + s];
  const int c  = cnts[b * S_ + s];
  const int t  = threadIdx.x;  // 0..191
  const int stride = D_ / 4;   // 192 float4 per row

  const float4* hp = (const float4*)(hidden + ((size_t)b * L_ + st) * D_) + t;
  float4 a0 = {0, 0, 0, 0}, a1 = a0, a2 = a0, a3 = a0;
  int l = 0;
  for (; l + 8 <= c; l += 8) {
    float4 v0 = hp[(size_t)(l + 0) * stride];
    float4 v1 = hp[(size_t)(l + 1) * stride];
    float4 v2 = hp[(size_t)(l + 2) * stride];
    float4 v3 = hp[(size_t)(l + 3) * stride];
    float4 v4 = hp[(size_t)(l + 4) * stride];
    float4 v5 = hp[(size_t)(l + 5) * stride];
    float4 v6 = hp[(size_t)(l + 6) * stride];
    float4 v7 = hp[(size_t)(l + 7) * stride];
    a0 = f4add(a0, v0); a1 = f4add(a1, v1);
    a2 = f4add(a2, v2); a3 = f4add(a3, v3);
    a0 = f4add(a0, v4); a1 = f4add(a1, v5);
    a2 = f4add(a2, v6); a3 = f4add(a3, v7);
  }
  for (; l < c; ++l) a0 = f4add(a0, hp[(size_t)l * stride]);
  a0 = f4add(f4add(a0, a1), f4add(a2, a3));

  const float inv = 1.0f / (float)max(c, 1);
  float o[4] = {a0.x * inv, a0.y * inv, a0.z * inv, a0.w * inv};
  ushort4 h, l4;
  h.x = f2bf(o[0]); l4.x = f2bf(o[0] - bf2f(h.x));
  h.y = f2bf(o[1]); l4.y = f2bf(o[1] - bf2f(h.y));
  h.z = f2bf(o[2]); l4.z = f2bf(o[2] - bf2f(h.z));
  h.w = f2bf(o[3]); l4.w = f2bf(o[3] - bf2f(h.w));
  const size_t idx = ((size_t)b * S_ + s) * D_ + t * 4;
  *(ushort4*)&mh[idx] = h;
  *(ushort4*)&ml[idx] = l4;
}

// ---------------------------------------------------------------------------
// Kernel 3: GEMM1 via MFMA, bf16 hi/lo 3-pass (hh+hl+lh ~ fp32 precision).
// A: [M][K] hi/lo. B: B^T [N][K] hi/lo. C = relu(A@B + bias) as hi/lo.
// 64x64 tile, 4 waves (2x2 of 32x32), double-buffered LDS.
// ---------------------------------------------------------------------------
__global__ __launch_bounds__(256) void gemm_mfma(
    const ushort* __restrict__ Ah, const ushort* __restrict__ Al,
    const ushort* __restrict__ Bh, const ushort* __restrict__ Bl,
    const float* __restrict__ bias, ushort* __restrict__ Ch,
    ushort* __restrict__ Cl, int M, int N, int K) {
  constexpr int LDA = 40;  // padded row stride: 2-way bank alias only (free)
  __shared__ __align__(16) ushort lds[2][4][64 * LDA];  // Ah, Al, Bh, Bl

  const int tid  = threadIdx.x;
  const int wid  = tid >> 6;
  const int lane = tid & 63;
  const int m0 = (wid >> 1) * 32;
  const int n0 = (wid & 1) * 32;
  const int lrow = lane & 15;
  const int lk   = (lane >> 4) * 8;

  const int srow = tid >> 2;        // 0..63
  const int sk   = (tid & 3) * 8;   // 0,8,16,24

  const int brow = blockIdx.y * 64;
  const int bcol = blockIdx.x * 64;

  const ushort* Aph = Ah + (size_t)(brow + srow) * K + sk;
  const ushort* Apl = Al + (size_t)(brow + srow) * K + sk;
  const ushort* Bph = Bh + (size_t)(bcol + srow) * K + sk;
  const ushort* Bpl = Bl + (size_t)(bcol + srow) * K + sk;

  const int NT = K / 32;
  const int soff = srow * LDA + sk;

  uint4 ra_h = *(const uint4*)Aph;
  uint4 ra_l = *(const uint4*)Apl;
  uint4 rb_h = *(const uint4*)Bph;
  uint4 rb_l = *(const uint4*)Bpl;
  *(uint4*)&lds[0][0][soff] = ra_h;
  *(uint4*)&lds[0][1][soff] = ra_l;
  *(uint4*)&lds[0][2][soff] = rb_h;
  *(uint4*)&lds[0][3][soff] = rb_l;
  __syncthreads();

  f32x4 acc[2][2] = {};

  for (int t = 0; t < NT; ++t) {
    const int cur = t & 1;
    if (t + 1 < NT) {
      ra_h = *(const uint4*)(Aph + (size_t)(t + 1) * 32);
      ra_l = *(const uint4*)(Apl + (size_t)(t + 1) * 32);
      rb_h = *(const uint4*)(Bph + (size_t)(t + 1) * 32);
      rb_l = *(const uint4*)(Bpl + (size_t)(t + 1) * 32);
    }
    short8 ah[2], al[2], bh[2], bl[2];
    #pragma unroll
    for (int i = 0; i < 2; ++i) {
      const int ro = (m0 + i * 16 + lrow) * LDA + lk;
      ah[i] = *(const short8*)&lds[cur][0][ro];
      al[i] = *(const short8*)&lds[cur][1][ro];
    }
    #pragma unroll
    for (int j = 0; j < 2; ++j) {
      const int ro = (n0 + j * 16 + lrow) * LDA + lk;
      bh[j] = *(const short8*)&lds[cur][2][ro];
      bl[j] = *(const short8*)&lds[cur][3][ro];
    }
    #pragma unroll
    for (int i = 0; i < 2; ++i)
      #pragma unroll
      for (int j = 0; j < 2; ++j) {
        acc[i][j] = __builtin_amdgcn_mfma_f32_16x16x32_bf16(ah[i], bh[j], acc[i][j], 0, 0, 0);
        acc[i][j] = __builtin_amdgcn_mfma_f32_16x16x32_bf16(ah[i], bl[j], acc[i][j], 0, 0, 0);
        acc[i][j] = __builtin_amdgcn_mfma_f32_16x16x32_bf16(al[i], bh[j], acc[i][j], 0, 0, 0);
      }
    if (t + 1 < NT) {
      __syncthreads();
      const int nxt = cur ^ 1;
      *(uint4*)&lds[nxt][0][soff] = ra_h;
      *(uint4*)&lds[nxt][1][soff] = ra_l;
      *(uint4*)&lds[nxt][2][soff] = rb_h;
      *(uint4*)&lds[nxt][3][soff] = rb_l;
      __syncthreads();
    }
  }

  // epilogue: bias + relu -> hi/lo; C/D layout col=lane&15, row=(lane>>4)*4+r
  #pragma unroll
  for (int i = 0; i < 2; ++i)
    #pragma unroll
    for (int j = 0; j < 2; ++j) {
      const float bj = bias[bcol + n0 + j * 16 + lrow];
      #pragma unroll
      for (int r = 0; r < 4; ++r) {
        float v = fmaxf(acc[i][j][r] + bj, 0.0f);
        const size_t idx =
            (size_t)(brow + m0 + i * 16 + (lane >> 4) * 4 + r) * N +
            bcol + n0 + j * 16 + lrow;
        ushort h = f2bf(v);
        Ch[idx] = h;
        Cl[idx] = f2bf(v - bf2f(h));
      }
    }
}

// ---------------------------------------------------------------------------
// Kernel 4: GEMM2 (h1 @ W2 + b2, relu) fused with final (@ W3 + b3).
// BM=64, BN=128 (full N2) -> h2 tile stays in registers; epilogue does the
// x W3 reduction via 16-lane shfl + LDS partials. Grid: M/64 = 64 blocks.
// ---------------------------------------------------------------------------
__global__ __launch_bounds__(256) void gemm2_final(
    const ushort* __restrict__ Ah, const ushort* __restrict__ Al,
    const ushort* __restrict__ Bh, const ushort* __restrict__ Bl,
    const float* __restrict__ b2, const float* __restrict__ W3,
    const float* __restrict__ b3, float* __restrict__ out) {
  constexpr int K = N1_;   // 384
  constexpr int LDA = 40;
  __shared__ __align__(16) ushort sA[2][2][64 * LDA];    // [buf][hi/lo]
  __shared__ __align__(16) ushort sB[2][2][128 * LDA];
  __shared__ float pl[64][2];

  const int tid  = threadIdx.x;
  const int wid  = tid >> 6;
  const int lane = tid & 63;
  const int m0 = (wid >> 1) * 32;   // 0 or 32
  const int n0 = (wid & 1) * 64;    // 0 or 64
  const int lrow = lane & 15;
  const int lk   = (lane >> 4) * 8;
  const int brow = blockIdx.x * 64;

  const int srA = tid >> 2, skA = (tid & 3) * 8;   // 64 rows x 32 k
  const int srB = tid >> 1, skB = (tid & 1) * 16;  // 128 rows x 32 k (2x uint4)

  const ushort* pAh = Ah + (size_t)(brow + srA) * K + skA;
  const ushort* pAl = Al + (size_t)(brow + srA) * K + skA;
  const ushort* pBh = Bh + (size_t)srB * K + skB;
  const ushort* pBl = Bl + (size_t)srB * K + skB;
  const int offA = srA * LDA + skA;
  const int offB = srB * LDA + skB;

  uint4 rah = *(const uint4*)pAh;
  uint4 ral = *(const uint4*)pAl;
  uint4 rbh0 = *(const uint4*)pBh;
  uint4 rbh1 = *(const uint4*)(pBh + 8);
  uint4 rbl0 = *(const uint4*)pBl;
  uint4 rbl1 = *(const uint4*)(pBl + 8);
  *(uint4*)&sA[0][0][offA] = rah;
  *(uint4*)&sA[0][1][offA] = ral;
  *(uint4*)&sB[0][0][offB] = rbh0;
  *(uint4*)&sB[0][0][offB + 8] = rbh1;
  *(uint4*)&sB[0][1][offB] = rbl0;
  *(uint4*)&sB[0][1][offB + 8] = rbl1;
  __syncthreads();

  f32x4 acc[2][4] = {};
  constexpr int NT = K / 32;  // 12

  for (int t = 0; t < NT; ++t) {
    const int cur = t & 1;
    if (t + 1 < NT) {
      rah  = *(const uint4*)(pAh + (size_t)(t + 1) * 32);
      ral  = *(const uint4*)(pAl + (size_t)(t + 1) * 32);
      rbh0 = *(const uint4*)(pBh + (size_t)(t + 1) * 32);
      rbh1 = *(const uint4*)(pBh + (size_t)(t + 1) * 32 + 8);
      rbl0 = *(const uint4*)(pBl + (size_t)(t + 1) * 32);
      rbl1 = *(const uint4*)(pBl + (size_t)(t + 1) * 32 + 8);
    }
    short8 ah[2], al[2], bh[4], bl[4];
    #pragma unroll
    for (int i = 0; i < 2; ++i) {
      const int ro = (m0 + i * 16 + lrow) * LDA + lk;
      ah[i] = *(const short8*)&sA[cur][0][ro];
      al[i] = *(const short8*)&sA[cur][1][ro];
    }
    #pragma unroll
    for (int j = 0; j < 4; ++j) {
      const int ro = (n0 + j * 16 + lrow) * LDA + lk;
      bh[j] = *(const short8*)&sB[cur][0][ro];
      bl[j] = *(const short8*)&sB[cur][1][ro];
    }
    #pragma unroll
    for (int i = 0; i < 2; ++i)
      #pragma unroll
      for (int j = 0; j < 4; ++j) {
        acc[i][j] = __builtin_amdgcn_mfma_f32_16x16x32_bf16(ah[i], bh[j], acc[i][j], 0, 0, 0);
        acc[i][j] = __builtin_amdgcn_mfma_f32_16x16x32_bf16(ah[i], bl[j], acc[i][j], 0, 0, 0);
        acc[i][j] = __builtin_amdgcn_mfma_f32_16x16x32_bf16(al[i], bh[j], acc[i][j], 0, 0, 0);
      }
    if (t + 1 < NT) {
      __syncthreads();
      const int nxt = cur ^ 1;
      *(uint4*)&sA[nxt][0][offA] = rah;
      *(uint4*)&sA[nxt][1][offA] = ral;
      *(uint4*)&sB[nxt][0][offB] = rbh0;
      *(uint4*)&sB[nxt][0][offB + 8] = rbh1;
      *(uint4*)&sB[nxt][1][offB] = rbl0;
      *(uint4*)&sB[nxt][1][offB + 8] = rbl1;
      __syncthreads();
    }
  }

  // ---- fused epilogue: h2 = relu(acc + b2); logits = h2 @ W3 + b3 ----
  __syncthreads();
  if (tid < 128) pl[tid >> 1][tid & 1] = 0.0f;
  float w3v[4][2], b2v[4];
  #pragma unroll
  for (int j = 0; j < 4; ++j) {
    const int col = n0 + j * 16 + lrow;
    w3v[j][0] = W3[col * 2 + 0];
    w3v[j][1] = W3[col * 2 + 1];
    b2v[j] = b2[col];
  }
  __syncthreads();
  #pragma unroll
  for (int i = 0; i < 2; ++i)
    #pragma unroll
    for (int r = 0; r < 4; ++r) {
      float p0 = 0.0f, p1 = 0.0f;
      #pragma unroll
      for (int j = 0; j < 4; ++j) {
        float v = fmaxf(acc[i][j][r] + b2v[j], 0.0f);
        p0 += v * w3v[j][0];
        p1 += v * w3v[j][1];
      }
      p0 += __shfl_xor(p0, 1); p1 += __shfl_xor(p1, 1);
      p0 += __shfl_xor(p0, 2); p1 += __shfl_xor(p1, 2);
      p0 += __shfl_xor(p0, 4); p1 += __shfl_xor(p1, 4);
      p0 += __shfl_xor(p0, 8); p1 += __shfl_xor(p1, 8);
      if (lrow == 0) {
        const int row = m0 + i * 16 + (lane >> 4) * 4 + r;
        atomicAdd(&pl[row][0], p0);
        atomicAdd(&pl[row][1], p1);
      }
    }
  __syncthreads();
  if (tid < 128) {
    const int row = tid >> 1, c = tid & 1;
    out[(size_t)(brow + row) * 2 + c] = pl[row][c] + b3[c];
  }
}

// ---------------------------------------------------------------------------
extern "C" void kernel_launch(void* const* d_in, const int* in_sizes, int n_in,
                              void* d_out, int out_size, void* d_ws, size_t ws_size,
                              hipStream_t stream) {
  const float* hidden  = (const float*)d_in[0];
  const int*   seg_ids = (const int*)d_in[1];
  const float* W1 = (const float*)d_in[2];
  const float* b1 = (const float*)d_in[3];
  const float* W2 = (const float*)d_in[4];
  const float* b2 = (const float*)d_in[5];
  const float* W3 = (const float*)d_in[6];
  const float* b3 = (const float*)d_in[7];
  float* out = (float*)d_out;

  // workspace layout (all 16B-aligned)
  char* p = (char*)d_ws;
  ushort* mh   = (ushort*)p;  p += (size_t)M_ * D_ * 2;
  ushort* ml   = (ushort*)p;  p += (size_t)M_ * D_ * 2;
  ushort* w1th = (ushort*)p;  p += (size_t)N1_ * D_ * 2;
  ushort* w1tl = (ushort*)p;  p += (size_t)N1_ * D_ * 2;
  ushort* h1h  = (ushort*)p;  p += (size_t)M_ * N1_ * 2;
  ushort* h1l  = (ushort*)p;  p += (size_t)M_ * N1_ * 2;
  ushort* w2th = (ushort*)p;  p += (size_t)N2_ * N1_ * 2;
  ushort* w2tl = (ushort*)p;  p += (size_t)N2_ * N1_ * 2;
  int* starts  = (int*)p;     p += (size_t)M_ * 4;
  int* cnts    = (int*)p;

  prep_kernel<<<B_ + 288 + 48, 256, 0, stream>>>(
      seg_ids, starts, cnts, W1, w1th, w1tl, W2, w2th, w2tl);
  seg_mean_kernel<<<dim3(S_, B_), 192, 0, stream>>>(hidden, starts, cnts, mh, ml);
  gemm_mfma<<<dim3(N1_ / 64, M_ / 64), 256, 0, stream>>>(
      mh, ml, w1th, w1tl, b1, h1h, h1l, M_, N1_, D_);
  gemm2_final<<<M_ / 64, 256, 0, stream>>>(
      h1h, h1l, w2th, w2tl, b2, W3, b3, out);
}

// Round 5
// 54.826 us; speedup vs baseline: 2.7813x; 1.1102x over previous
//
#include <hip/hip_runtime.h>

#define B_  64
#define L_  512
#define D_  768
#define S_  64
#define M_  (B_ * S_)   // 4096 output rows
#define N1_ 384
#define N2_ 128

typedef __attribute__((ext_vector_type(8))) short short8;
typedef __attribute__((ext_vector_type(4))) float f32x4;

__device__ __forceinline__ ushort f2bf(float x) {
  uint u = __float_as_uint(x);
  uint r = (u + 0x7fffu + ((u >> 16) & 1u)) >> 16;
  return (ushort)r;
}
__device__ __forceinline__ float bf2f(ushort h) {
  return __uint_as_float(((uint)h) << 16);
}
__device__ __forceinline__ float4 f4fma(float4 a, float4 v, float m) {
  return make_float4(fmaf(v.x, m, a.x), fmaf(v.y, m, a.y),
                     fmaf(v.z, m, a.z), fmaf(v.w, m, a.w));
}

// ---------------------------------------------------------------------------
// Kernel 1 (one launch): blocks 0..4095 -> segment mean for (s,b) incl. its
// own bounds scan; blocks 4096.. -> weight transpose + hi/lo split.
// ---------------------------------------------------------------------------
__global__ __launch_bounds__(192) void mean_prep_kernel(
    const float* __restrict__ hidden, const int* __restrict__ seg_ids,
    ushort* __restrict__ mh, ushort* __restrict__ ml,
    const float* __restrict__ W1, ushort* __restrict__ w1th,
    ushort* __restrict__ w1tl, const float* __restrict__ W2,
    ushort* __restrict__ w2th, ushort* __restrict__ w2tl) {
  const int bid = blockIdx.x;
  const int tid = threadIdx.x;

  if (bid < M_) {
    // ---- segment mean with inline bounds ----
    const int s = bid & 63;
    const int b = bid >> 6;
    __shared__ int sids[L_];
    __shared__ int wred[3];
    for (int i = tid; i < L_ / 4; i += 192)
      ((int4*)sids)[i] = ((const int4*)(seg_ids + b * L_))[i];
    __syncthreads();
    int stl = 0, cl = 0;
    for (int l = tid; l < L_; l += 192) {
      int v = sids[l];
      stl += (v < s) ? 1 : 0;
      cl  += (v == s) ? 1 : 0;
    }
    int packed = stl * 1024 + cl;   // st,c <= 512 each: fits
    #pragma unroll
    for (int off = 1; off < 64; off <<= 1) packed += __shfl_xor(packed, off);
    if ((tid & 63) == 0) wred[tid >> 6] = packed;
    __syncthreads();
    const int tot = wred[0] + wred[1] + wred[2];
    const int st = tot >> 10;
    const int c  = tot & 1023;

    // ---- 8-wide masked accumulate: all loads independent, no serial tail ----
    const float4* hp = (const float4*)(hidden + ((size_t)b * L_ + st) * D_) + tid;
    const int stride = D_ / 4;  // 192
    float4 a0 = {0, 0, 0, 0}, a1 = a0, a2 = a0, a3 = a0;
    for (int l = 0; l < c; l += 8) {
      const int i1 = min(l + 1, c - 1), i2 = min(l + 2, c - 1);
      const int i3 = min(l + 3, c - 1), i4 = min(l + 4, c - 1);
      const int i5 = min(l + 5, c - 1), i6 = min(l + 6, c - 1);
      const int i7 = min(l + 7, c - 1);
      float4 v0 = hp[(size_t)l  * stride];
      float4 v1 = hp[(size_t)i1 * stride];
      float4 v2 = hp[(size_t)i2 * stride];
      float4 v3 = hp[(size_t)i3 * stride];
      float4 v4 = hp[(size_t)i4 * stride];
      float4 v5 = hp[(size_t)i5 * stride];
      float4 v6 = hp[(size_t)i6 * stride];
      float4 v7 = hp[(size_t)i7 * stride];
      const float m1 = (l + 1 < c) ? 1.0f : 0.0f;
      const float m2 = (l + 2 < c) ? 1.0f : 0.0f;
      const float m3 = (l + 3 < c) ? 1.0f : 0.0f;
      const float m4 = (l + 4 < c) ? 1.0f : 0.0f;
      const float m5 = (l + 5 < c) ? 1.0f : 0.0f;
      const float m6 = (l + 6 < c) ? 1.0f : 0.0f;
      const float m7 = (l + 7 < c) ? 1.0f : 0.0f;
      a0 = f4fma(a0, v0, 1.0f); a1 = f4fma(a1, v1, m1);
      a2 = f4fma(a2, v2, m2);   a3 = f4fma(a3, v3, m3);
      a0 = f4fma(a0, v4, m4);   a1 = f4fma(a1, v5, m5);
      a2 = f4fma(a2, v6, m6);   a3 = f4fma(a3, v7, m7);
    }
    a0.x += a1.x + a2.x + a3.x; a0.y += a1.y + a2.y + a3.y;
    a0.z += a1.z + a2.z + a3.z; a0.w += a1.w + a2.w + a3.w;

    const float inv = 1.0f / (float)max(c, 1);
    float o[4] = {a0.x * inv, a0.y * inv, a0.z * inv, a0.w * inv};
    ushort4 h, l4;
    h.x = f2bf(o[0]); l4.x = f2bf(o[0] - bf2f(h.x));
    h.y = f2bf(o[1]); l4.y = f2bf(o[1] - bf2f(h.y));
    h.z = f2bf(o[2]); l4.z = f2bf(o[2] - bf2f(h.z));
    h.w = f2bf(o[3]); l4.w = f2bf(o[3] - bf2f(h.w));
    const size_t idx = ((size_t)b * S_ + s) * D_ + tid * 4;
    *(ushort4*)&mh[idx] = h;
    *(ushort4*)&ml[idx] = l4;
  } else {
    // ---- weight transpose + hi/lo split (32x32 tiles, 192 threads) ----
    int wb = bid - M_;
    const float* W; ushort *Wth, *Wtl; int K, N, nblk, kblk;
    if (wb < 288) {  // W1: 12 col-tiles x 24 row-tiles
      W = W1; Wth = w1th; Wtl = w1tl; K = D_; N = N1_;
      nblk = wb % 12; kblk = wb / 12;
    } else {         // W2: 4 x 12
      wb -= 288;
      W = W2; Wth = w2th; Wtl = w2tl; K = N1_; N = N2_;
      nblk = wb % 4; kblk = wb / 4;
    }
    __shared__ float tile[32][33];
    const int n0 = nblk * 32, k0 = kblk * 32;
    const int tx = tid & 31, ty = tid >> 5;  // 32 x 6
    for (int r = ty; r < 32; r += 6)
      tile[r][tx] = W[(size_t)(k0 + r) * N + n0 + tx];
    __syncthreads();
    for (int r = ty; r < 32; r += 6) {
      float x = tile[tx][r];  // W[k0+tx][n0+r]
      ushort h = f2bf(x);
      ushort lo = f2bf(x - bf2f(h));
      Wth[(size_t)(n0 + r) * K + k0 + tx] = h;
      Wtl[(size_t)(n0 + r) * K + k0 + tx] = lo;
    }
  }
}

// ---------------------------------------------------------------------------
// Kernel 2: GEMM1 via MFMA, bf16 hi/lo 3-pass (hh+hl+lh ~ fp32 precision).
// A: [M][K] hi/lo. B: B^T [N][K] hi/lo. C = relu(A@B + bias) as hi/lo.
// 64x64 tile, 4 waves (2x2 of 32x32), double-buffered LDS.
// ---------------------------------------------------------------------------
__global__ __launch_bounds__(256) void gemm_mfma(
    const ushort* __restrict__ Ah, const ushort* __restrict__ Al,
    const ushort* __restrict__ Bh, const ushort* __restrict__ Bl,
    const float* __restrict__ bias, ushort* __restrict__ Ch,
    ushort* __restrict__ Cl, int M, int N, int K) {
  constexpr int LDA = 40;  // padded row stride: 2-way bank alias only (free)
  __shared__ __align__(16) ushort lds[2][4][64 * LDA];  // Ah, Al, Bh, Bl

  const int tid  = threadIdx.x;
  const int wid  = tid >> 6;
  const int lane = tid & 63;
  const int m0 = (wid >> 1) * 32;
  const int n0 = (wid & 1) * 32;
  const int lrow = lane & 15;
  const int lk   = (lane >> 4) * 8;

  const int srow = tid >> 2;        // 0..63
  const int sk   = (tid & 3) * 8;   // 0,8,16,24

  const int brow = blockIdx.y * 64;
  const int bcol = blockIdx.x * 64;

  const ushort* Aph = Ah + (size_t)(brow + srow) * K + sk;
  const ushort* Apl = Al + (size_t)(brow + srow) * K + sk;
  const ushort* Bph = Bh + (size_t)(bcol + srow) * K + sk;
  const ushort* Bpl = Bl + (size_t)(bcol + srow) * K + sk;

  const int NT = K / 32;
  const int soff = srow * LDA + sk;

  uint4 ra_h = *(const uint4*)Aph;
  uint4 ra_l = *(const uint4*)Apl;
  uint4 rb_h = *(const uint4*)Bph;
  uint4 rb_l = *(const uint4*)Bpl;
  *(uint4*)&lds[0][0][soff] = ra_h;
  *(uint4*)&lds[0][1][soff] = ra_l;
  *(uint4*)&lds[0][2][soff] = rb_h;
  *(uint4*)&lds[0][3][soff] = rb_l;
  __syncthreads();

  f32x4 acc[2][2] = {};

  for (int t = 0; t < NT; ++t) {
    const int cur = t & 1;
    if (t + 1 < NT) {
      ra_h = *(const uint4*)(Aph + (size_t)(t + 1) * 32);
      ra_l = *(const uint4*)(Apl + (size_t)(t + 1) * 32);
      rb_h = *(const uint4*)(Bph + (size_t)(t + 1) * 32);
      rb_l = *(const uint4*)(Bpl + (size_t)(t + 1) * 32);
    }
    short8 ah[2], al[2], bh[2], bl[2];
    #pragma unroll
    for (int i = 0; i < 2; ++i) {
      const int ro = (m0 + i * 16 + lrow) * LDA + lk;
      ah[i] = *(const short8*)&lds[cur][0][ro];
      al[i] = *(const short8*)&lds[cur][1][ro];
    }
    #pragma unroll
    for (int j = 0; j < 2; ++j) {
      const int ro = (n0 + j * 16 + lrow) * LDA + lk;
      bh[j] = *(const short8*)&lds[cur][2][ro];
      bl[j] = *(const short8*)&lds[cur][3][ro];
    }
    #pragma unroll
    for (int i = 0; i < 2; ++i)
      #pragma unroll
      for (int j = 0; j < 2; ++j) {
        acc[i][j] = __builtin_amdgcn_mfma_f32_16x16x32_bf16(ah[i], bh[j], acc[i][j], 0, 0, 0);
        acc[i][j] = __builtin_amdgcn_mfma_f32_16x16x32_bf16(ah[i], bl[j], acc[i][j], 0, 0, 0);
        acc[i][j] = __builtin_amdgcn_mfma_f32_16x16x32_bf16(al[i], bh[j], acc[i][j], 0, 0, 0);
      }
    if (t + 1 < NT) {
      __syncthreads();
      const int nxt = cur ^ 1;
      *(uint4*)&lds[nxt][0][soff] = ra_h;
      *(uint4*)&lds[nxt][1][soff] = ra_l;
      *(uint4*)&lds[nxt][2][soff] = rb_h;
      *(uint4*)&lds[nxt][3][soff] = rb_l;
      __syncthreads();
    }
  }

  // epilogue: bias + relu -> hi/lo; C/D layout col=lane&15, row=(lane>>4)*4+r
  #pragma unroll
  for (int i = 0; i < 2; ++i)
    #pragma unroll
    for (int j = 0; j < 2; ++j) {
      const float bj = bias[bcol + n0 + j * 16 + lrow];
      #pragma unroll
      for (int r = 0; r < 4; ++r) {
        float v = fmaxf(acc[i][j][r] + bj, 0.0f);
        const size_t idx =
            (size_t)(brow + m0 + i * 16 + (lane >> 4) * 4 + r) * N +
            bcol + n0 + j * 16 + lrow;
        ushort h = f2bf(v);
        Ch[idx] = h;
        Cl[idx] = f2bf(v - bf2f(h));
      }
    }
}

// ---------------------------------------------------------------------------
// Kernel 3: GEMM2 (h1 @ W2 + b2, relu) fused with final (@ W3 + b3).
// BM=32, BN=128 (full N2): 128 blocks (2x CU coverage vs BM=64), 4 waves each
// own a 32-col slice; h2 tile in registers; epilogue reduces x W3 via shfl +
// LDS atomics. Grid: M/32 = 128 blocks.
// ---------------------------------------------------------------------------
__global__ __launch_bounds__(256) void gemm2_final(
    const ushort* __restrict__ Ah, const ushort* __restrict__ Al,
    const ushort* __restrict__ Bh, const ushort* __restrict__ Bl,
    const float* __restrict__ b2, const float* __restrict__ W3,
    const float* __restrict__ b3, float* __restrict__ out) {
  constexpr int K = N1_;   // 384
  constexpr int LDA = 40;
  __shared__ __align__(16) ushort sA[2][2][32 * LDA];    // [buf][hi/lo]
  __shared__ __align__(16) ushort sB[2][2][128 * LDA];
  __shared__ float pl[32][2];

  const int tid  = threadIdx.x;
  const int wid  = tid >> 6;
  const int lane = tid & 63;
  const int n0 = wid * 32;          // wave's 32-col slice of N2=128
  const int lrow = lane & 15;
  const int lk   = (lane >> 4) * 8;
  const int brow = blockIdx.x * 32;

  // A staging: 32 rows x 32 k; threads 0..127 -> hi, 128..255 -> lo
  const int t7  = tid & 127;
  const int srA = t7 >> 2, skA = (t7 & 3) * 8;
  const ushort* pA = ((tid < 128) ? Ah : Al) + (size_t)(brow + srA) * K + skA;
  const int offA = srA * LDA + skA;
  const int abuf = (tid < 128) ? 0 : 1;
  // B staging: 128 rows x 32 k; each thread 2 uint4 per hi and lo
  const int srB = tid >> 1, skB = (tid & 1) * 16;
  const ushort* pBh = Bh + (size_t)srB * K + skB;
  const ushort* pBl = Bl + (size_t)srB * K + skB;
  const int offB = srB * LDA + skB;

  uint4 ra   = *(const uint4*)pA;
  uint4 rbh0 = *(const uint4*)pBh;
  uint4 rbh1 = *(const uint4*)(pBh + 8);
  uint4 rbl0 = *(const uint4*)pBl;
  uint4 rbl1 = *(const uint4*)(pBl + 8);
  *(uint4*)&sA[0][abuf][offA] = ra;
  *(uint4*)&sB[0][0][offB] = rbh0;
  *(uint4*)&sB[0][0][offB + 8] = rbh1;
  *(uint4*)&sB[0][1][offB] = rbl0;
  *(uint4*)&sB[0][1][offB + 8] = rbl1;
  __syncthreads();

  f32x4 acc[2][2] = {};   // i: 2 row-frags (32 rows), j: 2 col-frags (32 cols)
  constexpr int NT = K / 32;  // 12

  for (int t = 0; t < NT; ++t) {
    const int cur = t & 1;
    if (t + 1 < NT) {
      ra   = *(const uint4*)(pA  + (size_t)(t + 1) * 32);
      rbh0 = *(const uint4*)(pBh + (size_t)(t + 1) * 32);
      rbh1 = *(const uint4*)(pBh + (size_t)(t + 1) * 32 + 8);
      rbl0 = *(const uint4*)(pBl + (size_t)(t + 1) * 32);
      rbl1 = *(const uint4*)(pBl + (size_t)(t + 1) * 32 + 8);
    }
    short8 ah[2], al[2], bh[2], bl[2];
    #pragma unroll
    for (int i = 0; i < 2; ++i) {
      const int ro = (i * 16 + lrow) * LDA + lk;
      ah[i] = *(const short8*)&sA[cur][0][ro];
      al[i] = *(const short8*)&sA[cur][1][ro];
    }
    #pragma unroll
    for (int j = 0; j < 2; ++j) {
      const int ro = (n0 + j * 16 + lrow) * LDA + lk;
      bh[j] = *(const short8*)&sB[cur][0][ro];
      bl[j] = *(const short8*)&sB[cur][1][ro];
    }
    #pragma unroll
    for (int i = 0; i < 2; ++i)
      #pragma unroll
      for (int j = 0; j < 2; ++j) {
        acc[i][j] = __builtin_amdgcn_mfma_f32_16x16x32_bf16(ah[i], bh[j], acc[i][j], 0, 0, 0);
        acc[i][j] = __builtin_amdgcn_mfma_f32_16x16x32_bf16(ah[i], bl[j], acc[i][j], 0, 0, 0);
        acc[i][j] = __builtin_amdgcn_mfma_f32_16x16x32_bf16(al[i], bh[j], acc[i][j], 0, 0, 0);
      }
    if (t + 1 < NT) {
      __syncthreads();
      const int nxt = cur ^ 1;
      *(uint4*)&sA[nxt][abuf][offA] = ra;
      *(uint4*)&sB[nxt][0][offB] = rbh0;
      *(uint4*)&sB[nxt][0][offB + 8] = rbh1;
      *(uint4*)&sB[nxt][1][offB] = rbl0;
      *(uint4*)&sB[nxt][1][offB + 8] = rbl1;
      __syncthreads();
    }
  }

  // ---- fused epilogue: h2 = relu(acc + b2); logits = h2 @ W3 + b3 ----
  __syncthreads();
  if (tid < 64) pl[tid >> 1][tid & 1] = 0.0f;
  float w3v[2][2], b2v[2];
  #pragma unroll
  for (int j = 0; j < 2; ++j) {
    const int col = n0 + j * 16 + lrow;
    w3v[j][0] = W3[col * 2 + 0];
    w3v[j][1] = W3[col * 2 + 1];
    b2v[j] = b2[col];
  }
  __syncthreads();
  #pragma unroll
  for (int i = 0; i < 2; ++i)
    #pragma unroll
    for (int r = 0; r < 4; ++r) {
      float p0 = 0.0f, p1 = 0.0f;
      #pragma unroll
      for (int j = 0; j < 2; ++j) {
        float v = fmaxf(acc[i][j][r] + b2v[j], 0.0f);
        p0 += v * w3v[j][0];
        p1 += v * w3v[j][1];
      }
      p0 += __shfl_xor(p0, 1); p1 += __shfl_xor(p1, 1);
      p0 += __shfl_xor(p0, 2); p1 += __shfl_xor(p1, 2);
      p0 += __shfl_xor(p0, 4); p1 += __shfl_xor(p1, 4);
      p0 += __shfl_xor(p0, 8); p1 += __shfl_xor(p1, 8);
      if (lrow == 0) {
        const int row = i * 16 + (lane >> 4) * 4 + r;
        atomicAdd(&pl[row][0], p0);
        atomicAdd(&pl[row][1], p1);
      }
    }
  __syncthreads();
  if (tid < 64) {
    const int row = tid >> 1, c = tid & 1;
    out[(size_t)(brow + row) * 2 + c] = pl[row][c] + b3[c];
  }
}

// ---------------------------------------------------------------------------
extern "C" void kernel_launch(void* const* d_in, const int* in_sizes, int n_in,
                              void* d_out, int out_size, void* d_ws, size_t ws_size,
                              hipStream_t stream) {
  const float* hidden  = (const float*)d_in[0];
  const int*   seg_ids = (const int*)d_in[1];
  const float* W1 = (const float*)d_in[2];
  const float* b1 = (const float*)d_in[3];
  const float* W2 = (const float*)d_in[4];
  const float* b2 = (const float*)d_in[5];
  const float* W3 = (const float*)d_in[6];
  const float* b3 = (const float*)d_in[7];
  float* out = (float*)d_out;

  // workspace layout (all 16B-aligned)
  char* p = (char*)d_ws;
  ushort* mh   = (ushort*)p;  p += (size_t)M_ * D_ * 2;
  ushort* ml   = (ushort*)p;  p += (size_t)M_ * D_ * 2;
  ushort* w1th = (ushort*)p;  p += (size_t)N1_ * D_ * 2;
  ushort* w1tl = (ushort*)p;  p += (size_t)N1_ * D_ * 2;
  ushort* h1h  = (ushort*)p;  p += (size_t)M_ * N1_ * 2;
  ushort* h1l  = (ushort*)p;  p += (size_t)M_ * N1_ * 2;
  ushort* w2th = (ushort*)p;  p += (size_t)N2_ * N1_ * 2;
  ushort* w2tl = (ushort*)p;  p += (size_t)N2_ * N1_ * 2;

  mean_prep_kernel<<<M_ + 288 + 48, 192, 0, stream>>>(
      hidden, seg_ids, mh, ml, W1, w1th, w1tl, W2, w2th, w2tl);
  gemm_mfma<<<dim3(N1_ / 64, M_ / 64), 256, 0, stream>>>(
      mh, ml, w1th, w1tl, b1, h1h, h1l, M_, N1_, D_);
  gemm2_final<<<M_ / 32, 256, 0, stream>>>(
      h1h, h1l, w2th, w2tl, b2, W3, b3, out);
}

// Round 6
// 51.072 us; speedup vs baseline: 2.9857x; 1.0735x over previous
//
#include <hip/hip_runtime.h>

#define B_  64
#define L_  512
#define D_  768
#define S_  64
#define M_  (B_ * S_)   // 4096 output rows
#define N1_ 384
#define N2_ 128

typedef __attribute__((ext_vector_type(8))) short short8;
typedef __attribute__((ext_vector_type(4))) float f32x4;

__device__ __forceinline__ ushort f2bf(float x) {
  uint u = __float_as_uint(x);
  uint r = (u + 0x7fffu + ((u >> 16) & 1u)) >> 16;
  return (ushort)r;
}
__device__ __forceinline__ float bf2f(ushort h) {
  return __uint_as_float(((uint)h) << 16);
}
__device__ __forceinline__ float4 f4fma(float4 a, float4 v, float m) {
  return make_float4(fmaf(v.x, m, a.x), fmaf(v.y, m, a.y),
                     fmaf(v.z, m, a.z), fmaf(v.w, m, a.w));
}

// ---------------------------------------------------------------------------
// Kernel 1 (one launch): blocks 0..4095 -> segment mean for (s,b) incl. its
// own bounds scan (register-only + shfl); blocks 4096.. -> weight split.
// ---------------------------------------------------------------------------
__global__ __launch_bounds__(192) void mean_prep_kernel(
    const float* __restrict__ hidden, const int* __restrict__ seg_ids,
    ushort* __restrict__ mh, ushort* __restrict__ ml,
    const float* __restrict__ W1, ushort* __restrict__ w1th,
    ushort* __restrict__ w1tl, const float* __restrict__ W2,
    ushort* __restrict__ w2th, ushort* __restrict__ w2tl) {
  const int bid = blockIdx.x;
  const int tid = threadIdx.x;

  if (bid < M_) {
    // ---- bounds scan: 128 threads each load one int4, count in regs ----
    const int s = bid & 63;
    const int b = bid >> 6;
    int stl = 0, cl = 0;
    if (tid < 128) {
      int4 v = ((const int4*)(seg_ids + b * L_))[tid];
      stl = (v.x < s) + (v.y < s) + (v.z < s) + (v.w < s);
      cl  = (v.x == s) + (v.y == s) + (v.z == s) + (v.w == s);
    }
    int packed = stl * 1024 + cl;   // st,c <= 512 each: fits
    #pragma unroll
    for (int off = 1; off < 64; off <<= 1) packed += __shfl_xor(packed, off);
    __shared__ int wred[3];
    if ((tid & 63) == 0) wred[tid >> 6] = packed;
    __syncthreads();
    const int tot = wred[0] + wred[1] + wred[2];
    const int st = tot >> 10;
    const int c  = tot & 1023;

    // ---- 8-wide masked accumulate: all loads independent, no serial tail ----
    const float4* hp = (const float4*)(hidden + ((size_t)b * L_ + st) * D_) + tid;
    const int stride = D_ / 4;  // 192
    float4 a0 = {0, 0, 0, 0}, a1 = a0, a2 = a0, a3 = a0;
    for (int l = 0; l < c; l += 8) {
      const int i1 = min(l + 1, c - 1), i2 = min(l + 2, c - 1);
      const int i3 = min(l + 3, c - 1), i4 = min(l + 4, c - 1);
      const int i5 = min(l + 5, c - 1), i6 = min(l + 6, c - 1);
      const int i7 = min(l + 7, c - 1);
      float4 v0 = hp[(size_t)l  * stride];
      float4 v1 = hp[(size_t)i1 * stride];
      float4 v2 = hp[(size_t)i2 * stride];
      float4 v3 = hp[(size_t)i3 * stride];
      float4 v4 = hp[(size_t)i4 * stride];
      float4 v5 = hp[(size_t)i5 * stride];
      float4 v6 = hp[(size_t)i6 * stride];
      float4 v7 = hp[(size_t)i7 * stride];
      const float m1 = (l + 1 < c) ? 1.0f : 0.0f;
      const float m2 = (l + 2 < c) ? 1.0f : 0.0f;
      const float m3 = (l + 3 < c) ? 1.0f : 0.0f;
      const float m4 = (l + 4 < c) ? 1.0f : 0.0f;
      const float m5 = (l + 5 < c) ? 1.0f : 0.0f;
      const float m6 = (l + 6 < c) ? 1.0f : 0.0f;
      const float m7 = (l + 7 < c) ? 1.0f : 0.0f;
      a0 = f4fma(a0, v0, 1.0f); a1 = f4fma(a1, v1, m1);
      a2 = f4fma(a2, v2, m2);   a3 = f4fma(a3, v3, m3);
      a0 = f4fma(a0, v4, m4);   a1 = f4fma(a1, v5, m5);
      a2 = f4fma(a2, v6, m6);   a3 = f4fma(a3, v7, m7);
    }
    a0.x += a1.x + a2.x + a3.x; a0.y += a1.y + a2.y + a3.y;
    a0.z += a1.z + a2.z + a3.z; a0.w += a1.w + a2.w + a3.w;

    const float inv = 1.0f / (float)max(c, 1);
    float o[4] = {a0.x * inv, a0.y * inv, a0.z * inv, a0.w * inv};
    ushort4 h, l4;
    h.x = f2bf(o[0]); l4.x = f2bf(o[0] - bf2f(h.x));
    h.y = f2bf(o[1]); l4.y = f2bf(o[1] - bf2f(h.y));
    h.z = f2bf(o[2]); l4.z = f2bf(o[2] - bf2f(h.z));
    h.w = f2bf(o[3]); l4.w = f2bf(o[3] - bf2f(h.w));
    const size_t idx = ((size_t)b * S_ + s) * D_ + tid * 4;
    *(ushort4*)&mh[idx] = h;
    *(ushort4*)&ml[idx] = l4;
  } else {
    // ---- weight transpose + hi/lo split (32x32 tiles, 192 threads) ----
    int wb = bid - M_;
    const float* W; ushort *Wth, *Wtl; int K, N, nblk, kblk;
    if (wb < 288) {  // W1: 12 col-tiles x 24 row-tiles
      W = W1; Wth = w1th; Wtl = w1tl; K = D_; N = N1_;
      nblk = wb % 12; kblk = wb / 12;
    } else {         // W2: 4 x 12
      wb -= 288;
      W = W2; Wth = w2th; Wtl = w2tl; K = N1_; N = N2_;
      nblk = wb % 4; kblk = wb / 4;
    }
    __shared__ float tile[32][33];
    const int n0 = nblk * 32, k0 = kblk * 32;
    const int tx = tid & 31, ty = tid >> 5;  // 32 x 6
    for (int r = ty; r < 32; r += 6)
      tile[r][tx] = W[(size_t)(k0 + r) * N + n0 + tx];
    __syncthreads();
    for (int r = ty; r < 32; r += 6) {
      float x = tile[tx][r];  // W[k0+tx][n0+r]
      ushort h = f2bf(x);
      ushort lo = f2bf(x - bf2f(h));
      Wth[(size_t)(n0 + r) * K + k0 + tx] = h;
      Wtl[(size_t)(n0 + r) * K + k0 + tx] = lo;
    }
  }
}

// ---------------------------------------------------------------------------
// Kernel 2: GEMM1 via MFMA, bf16 hi/lo 3-pass, 8 waves with K-split.
// BK=64 per stage: waves 0-3 consume kk 0..31, waves 4-7 kk 32..63.
// Single 36KB LDS buffer, 2 barriers per BK=64 (half the barriers of R5).
// Epilogue: waves 4-7 dump partial acc to LDS, waves 0-3 combine + store.
// Grid (N/64, M/64) = 384 blocks x 512 threads -> 12 waves/CU resident.
// ---------------------------------------------------------------------------
__global__ __launch_bounds__(512) void gemm_mfma8(
    const ushort* __restrict__ Ah, const ushort* __restrict__ Al,
    const ushort* __restrict__ Bh, const ushort* __restrict__ Bl,
    const float* __restrict__ bias, ushort* __restrict__ Ch,
    ushort* __restrict__ Cl, int M, int N, int K) {
  constexpr int LDK = 72;  // 64 + 8 pad: frag-read rows 2-way alias only
  __shared__ __align__(16) ushort smem[4 * 64 * LDK];  // 36,864 B
  ushort* sAh = smem;
  ushort* sAl = smem + 64 * LDK;
  ushort* sBh = smem + 2 * 64 * LDK;
  ushort* sBl = smem + 3 * 64 * LDK;

  const int tid  = threadIdx.x;
  const int wid  = tid >> 6;
  const int lane = tid & 63;
  const int w2 = wid & 3;
  const int kh = (wid >> 2) * 32;       // K-split: 0 or 32 within BK=64
  const int m0 = (w2 >> 1) * 32;
  const int n0 = (w2 & 1) * 32;
  const int lrow = lane & 15;
  const int lk   = (lane >> 4) * 8;

  const int srow = tid >> 3;            // 0..63
  const int sk   = (tid & 7) * 8;       // 0..56
  const int soff = srow * LDK + sk;

  const int brow = blockIdx.y * 64;
  const int bcol = blockIdx.x * 64;

  const ushort* Aph = Ah + (size_t)(brow + srow) * K + sk;
  const ushort* Apl = Al + (size_t)(brow + srow) * K + sk;
  const ushort* Bph = Bh + (size_t)(bcol + srow) * K + sk;
  const ushort* Bpl = Bl + (size_t)(bcol + srow) * K + sk;

  const int NT = K / 64;   // 12 for K=768

  uint4 ra_h = *(const uint4*)Aph;
  uint4 ra_l = *(const uint4*)Apl;
  uint4 rb_h = *(const uint4*)Bph;
  uint4 rb_l = *(const uint4*)Bpl;

  f32x4 acc[2][2] = {};

  for (int t = 0; t < NT; ++t) {
    *(uint4*)&sAh[soff] = ra_h;
    *(uint4*)&sAl[soff] = ra_l;
    *(uint4*)&sBh[soff] = rb_h;
    *(uint4*)&sBl[soff] = rb_l;
    __syncthreads();
    if (t + 1 < NT) {
      ra_h = *(const uint4*)(Aph + (size_t)(t + 1) * 64);
      ra_l = *(const uint4*)(Apl + (size_t)(t + 1) * 64);
      rb_h = *(const uint4*)(Bph + (size_t)(t + 1) * 64);
      rb_l = *(const uint4*)(Bpl + (size_t)(t + 1) * 64);
    }
    short8 ah[2], al[2], bh[2], bl[2];
    #pragma unroll
    for (int i = 0; i < 2; ++i) {
      const int ro = (m0 + i * 16 + lrow) * LDK + kh + lk;
      ah[i] = *(const short8*)&sAh[ro];
      al[i] = *(const short8*)&sAl[ro];
    }
    #pragma unroll
    for (int j = 0; j < 2; ++j) {
      const int ro = (n0 + j * 16 + lrow) * LDK + kh + lk;
      bh[j] = *(const short8*)&sBh[ro];
      bl[j] = *(const short8*)&sBl[ro];
    }
    #pragma unroll
    for (int i = 0; i < 2; ++i)
      #pragma unroll
      for (int j = 0; j < 2; ++j) {
        acc[i][j] = __builtin_amdgcn_mfma_f32_16x16x32_bf16(ah[i], bh[j], acc[i][j], 0, 0, 0);
        acc[i][j] = __builtin_amdgcn_mfma_f32_16x16x32_bf16(ah[i], bl[j], acc[i][j], 0, 0, 0);
        acc[i][j] = __builtin_amdgcn_mfma_f32_16x16x32_bf16(al[i], bh[j], acc[i][j], 0, 0, 0);
      }
    __syncthreads();
  }

  // ---- combine K-split partials through LDS (stride 18 dwords: 2-way) ----
  float* red = (float*)smem;
  const int roff = (w2 * 64 + lane) * 18;
  if (wid >= 4) {
    #pragma unroll
    for (int i = 0; i < 2; ++i)
      #pragma unroll
      for (int j = 0; j < 2; ++j) {
        *(float2*)&red[roff + i * 8 + j * 4]     = make_float2(acc[i][j][0], acc[i][j][1]);
        *(float2*)&red[roff + i * 8 + j * 4 + 2] = make_float2(acc[i][j][2], acc[i][j][3]);
      }
  }
  __syncthreads();
  if (wid < 4) {
    #pragma unroll
    for (int i = 0; i < 2; ++i)
      #pragma unroll
      for (int j = 0; j < 2; ++j) {
        float2 p0 = *(float2*)&red[roff + i * 8 + j * 4];
        float2 p1 = *(float2*)&red[roff + i * 8 + j * 4 + 2];
        acc[i][j][0] += p0.x; acc[i][j][1] += p0.y;
        acc[i][j][2] += p1.x; acc[i][j][3] += p1.y;
        const float bj = bias[bcol + n0 + j * 16 + lrow];
        #pragma unroll
        for (int r = 0; r < 4; ++r) {
          float v = fmaxf(acc[i][j][r] + bj, 0.0f);
          const size_t idx =
              (size_t)(brow + m0 + i * 16 + (lane >> 4) * 4 + r) * N +
              bcol + n0 + j * 16 + lrow;
          ushort h = f2bf(v);
          Ch[idx] = h;
          Cl[idx] = f2bf(v - bf2f(h));
        }
      }
  }
}

// ---------------------------------------------------------------------------
// Kernel 3: GEMM2 (h1 @ W2 + b2, relu) fused with final (@ W3 + b3).
// BM=32, BN=128 (full N2): 128 blocks, 4 waves each own a 32-col slice;
// h2 tile in registers; epilogue reduces x W3 via shfl + LDS atomics.
// ---------------------------------------------------------------------------
__global__ __launch_bounds__(256) void gemm2_final(
    const ushort* __restrict__ Ah, const ushort* __restrict__ Al,
    const ushort* __restrict__ Bh, const ushort* __restrict__ Bl,
    const float* __restrict__ b2, const float* __restrict__ W3,
    const float* __restrict__ b3, float* __restrict__ out) {
  constexpr int K = N1_;   // 384
  constexpr int LDA = 40;
  __shared__ __align__(16) ushort sA[2][2][32 * LDA];    // [buf][hi/lo]
  __shared__ __align__(16) ushort sB[2][2][128 * LDA];
  __shared__ float pl[32][2];

  const int tid  = threadIdx.x;
  const int wid  = tid >> 6;
  const int lane = tid & 63;
  const int n0 = wid * 32;          // wave's 32-col slice of N2=128
  const int lrow = lane & 15;
  const int lk   = (lane >> 4) * 8;
  const int brow = blockIdx.x * 32;

  // A staging: 32 rows x 32 k; threads 0..127 -> hi, 128..255 -> lo
  const int t7  = tid & 127;
  const int srA = t7 >> 2, skA = (t7 & 3) * 8;
  const ushort* pA = ((tid < 128) ? Ah : Al) + (size_t)(brow + srA) * K + skA;
  const int offA = srA * LDA + skA;
  const int abuf = (tid < 128) ? 0 : 1;
  // B staging: 128 rows x 32 k; each thread 2 uint4 per hi and lo
  const int srB = tid >> 1, skB = (tid & 1) * 16;
  const ushort* pBh = Bh + (size_t)srB * K + skB;
  const ushort* pBl = Bl + (size_t)srB * K + skB;
  const int offB = srB * LDA + skB;

  uint4 ra   = *(const uint4*)pA;
  uint4 rbh0 = *(const uint4*)pBh;
  uint4 rbh1 = *(const uint4*)(pBh + 8);
  uint4 rbl0 = *(const uint4*)pBl;
  uint4 rbl1 = *(const uint4*)(pBl + 8);
  *(uint4*)&sA[0][abuf][offA] = ra;
  *(uint4*)&sB[0][0][offB] = rbh0;
  *(uint4*)&sB[0][0][offB + 8] = rbh1;
  *(uint4*)&sB[0][1][offB] = rbl0;
  *(uint4*)&sB[0][1][offB + 8] = rbl1;
  __syncthreads();

  f32x4 acc[2][2] = {};   // i: 2 row-frags (32 rows), j: 2 col-frags (32 cols)
  constexpr int NT = K / 32;  // 12

  for (int t = 0; t < NT; ++t) {
    const int cur = t & 1;
    if (t + 1 < NT) {
      ra   = *(const uint4*)(pA  + (size_t)(t + 1) * 32);
      rbh0 = *(const uint4*)(pBh + (size_t)(t + 1) * 32);
      rbh1 = *(const uint4*)(pBh + (size_t)(t + 1) * 32 + 8);
      rbl0 = *(const uint4*)(pBl + (size_t)(t + 1) * 32);
      rbl1 = *(const uint4*)(pBl + (size_t)(t + 1) * 32 + 8);
    }
    short8 ah[2], al[2], bh[2], bl[2];
    #pragma unroll
    for (int i = 0; i < 2; ++i) {
      const int ro = (i * 16 + lrow) * LDA + lk;
      ah[i] = *(const short8*)&sA[cur][0][ro];
      al[i] = *(const short8*)&sA[cur][1][ro];
    }
    #pragma unroll
    for (int j = 0; j < 2; ++j) {
      const int ro = (n0 + j * 16 + lrow) * LDA + lk;
      bh[j] = *(const short8*)&sB[cur][0][ro];
      bl[j] = *(const short8*)&sB[cur][1][ro];
    }
    #pragma unroll
    for (int i = 0; i < 2; ++i)
      #pragma unroll
      for (int j = 0; j < 2; ++j) {
        acc[i][j] = __builtin_amdgcn_mfma_f32_16x16x32_bf16(ah[i], bh[j], acc[i][j], 0, 0, 0);
        acc[i][j] = __builtin_amdgcn_mfma_f32_16x16x32_bf16(ah[i], bl[j], acc[i][j], 0, 0, 0);
        acc[i][j] = __builtin_amdgcn_mfma_f32_16x16x32_bf16(al[i], bh[j], acc[i][j], 0, 0, 0);
      }
    if (t + 1 < NT) {
      __syncthreads();
      const int nxt = cur ^ 1;
      *(uint4*)&sA[nxt][abuf][offA] = ra;
      *(uint4*)&sB[nxt][0][offB] = rbh0;
      *(uint4*)&sB[nxt][0][offB + 8] = rbh1;
      *(uint4*)&sB[nxt][1][offB] = rbl0;
      *(uint4*)&sB[nxt][1][offB + 8] = rbl1;
      __syncthreads();
    }
  }

  // ---- fused epilogue: h2 = relu(acc + b2); logits = h2 @ W3 + b3 ----
  __syncthreads();
  if (tid < 64) pl[tid >> 1][tid & 1] = 0.0f;
  float w3v[2][2], b2v[2];
  #pragma unroll
  for (int j = 0; j < 2; ++j) {
    const int col = n0 + j * 16 + lrow;
    w3v[j][0] = W3[col * 2 + 0];
    w3v[j][1] = W3[col * 2 + 1];
    b2v[j] = b2[col];
  }
  __syncthreads();
  #pragma unroll
  for (int i = 0; i < 2; ++i)
    #pragma unroll
    for (int r = 0; r < 4; ++r) {
      float p0 = 0.0f, p1 = 0.0f;
      #pragma unroll
      for (int j = 0; j < 2; ++j) {
        float v = fmaxf(acc[i][j][r] + b2v[j], 0.0f);
        p0 += v * w3v[j][0];
        p1 += v * w3v[j][1];
      }
      p0 += __shfl_xor(p0, 1); p1 += __shfl_xor(p1, 1);
      p0 += __shfl_xor(p0, 2); p1 += __shfl_xor(p1, 2);
      p0 += __shfl_xor(p0, 4); p1 += __shfl_xor(p1, 4);
      p0 += __shfl_xor(p0, 8); p1 += __shfl_xor(p1, 8);
      if (lrow == 0) {
        const int row = i * 16 + (lane >> 4) * 4 + r;
        atomicAdd(&pl[row][0], p0);
        atomicAdd(&pl[row][1], p1);
      }
    }
  __syncthreads();
  if (tid < 64) {
    const int row = tid >> 1, c = tid & 1;
    out[(size_t)(brow + row) * 2 + c] = pl[row][c] + b3[c];
  }
}

// ---------------------------------------------------------------------------
extern "C" void kernel_launch(void* const* d_in, const int* in_sizes, int n_in,
                              void* d_out, int out_size, void* d_ws, size_t ws_size,
                              hipStream_t stream) {
  const float* hidden  = (const float*)d_in[0];
  const int*   seg_ids = (const int*)d_in[1];
  const float* W1 = (const float*)d_in[2];
  const float* b1 = (const float*)d_in[3];
  const float* W2 = (const float*)d_in[4];
  const float* b2 = (const float*)d_in[5];
  const float* W3 = (const float*)d_in[6];
  const float* b3 = (const float*)d_in[7];
  float* out = (float*)d_out;

  // workspace layout (all 16B-aligned)
  char* p = (char*)d_ws;
  ushort* mh   = (ushort*)p;  p += (size_t)M_ * D_ * 2;
  ushort* ml   = (ushort*)p;  p += (size_t)M_ * D_ * 2;
  ushort* w1th = (ushort*)p;  p += (size_t)N1_ * D_ * 2;
  ushort* w1tl = (ushort*)p;  p += (size_t)N1_ * D_ * 2;
  ushort* h1h  = (ushort*)p;  p += (size_t)M_ * N1_ * 2;
  ushort* h1l  = (ushort*)p;  p += (size_t)M_ * N1_ * 2;
  ushort* w2th = (ushort*)p;  p += (size_t)N2_ * N1_ * 2;
  ushort* w2tl = (ushort*)p;  p += (size_t)N2_ * N1_ * 2;

  mean_prep_kernel<<<M_ + 288 + 48, 192, 0, stream>>>(
      hidden, seg_ids, mh, ml, W1, w1th, w1tl, W2, w2th, w2tl);
  gemm_mfma8<<<dim3(N1_ / 64, M_ / 64), 512, 0, stream>>>(
      mh, ml, w1th, w1tl, b1, h1h, h1l, M_, N1_, D_);
  gemm2_final<<<M_ / 32, 256, 0, stream>>>(
      h1h, h1l, w2th, w2tl, b2, W3, b3, out);
}

// Round 7
// 47.831 us; speedup vs baseline: 3.1880x; 1.0678x over previous
//
#include <hip/hip_runtime.h>
#include <hip/hip_fp16.h>

#define B_  64
#define L_  512
#define D_  768
#define S_  64
#define M_  (B_ * S_)   // 4096 output rows
#define N1_ 384
#define N2_ 128

typedef __attribute__((ext_vector_type(8))) _Float16 half8;
typedef __attribute__((ext_vector_type(4))) float f32x4;

__device__ __forceinline__ ushort f2h(float x) {
  return __half_as_ushort(__float2half_rn(x));
}
__device__ __forceinline__ float h2f(ushort u) {
  return __half2float(__ushort_as_half(u));
}
__device__ __forceinline__ float4 f4fma(float4 a, float4 v, float m) {
  return make_float4(fmaf(v.x, m, a.x), fmaf(v.y, m, a.y),
                     fmaf(v.z, m, a.z), fmaf(v.w, m, a.w));
}

// ---------------------------------------------------------------------------
// Kernel 1 (one launch): blocks 0..4095 -> segment mean for (s,b) incl. its
// own bounds scan (register-only + shfl), output = f16 hi/lo split;
// blocks 4096.. -> weight transpose to B^T layout, single f16.
// ---------------------------------------------------------------------------
__global__ __launch_bounds__(192) void mean_prep_kernel(
    const float* __restrict__ hidden, const int* __restrict__ seg_ids,
    ushort* __restrict__ mh, ushort* __restrict__ ml,
    const float* __restrict__ W1, ushort* __restrict__ w1t,
    const float* __restrict__ W2, ushort* __restrict__ w2t) {
  const int bid = blockIdx.x;
  const int tid = threadIdx.x;

  if (bid < M_) {
    // ---- bounds scan: 128 threads each load one int4, count in regs ----
    const int s = bid & 63;
    const int b = bid >> 6;
    int stl = 0, cl = 0;
    if (tid < 128) {
      int4 v = ((const int4*)(seg_ids + b * L_))[tid];
      stl = (v.x < s) + (v.y < s) + (v.z < s) + (v.w < s);
      cl  = (v.x == s) + (v.y == s) + (v.z == s) + (v.w == s);
    }
    int packed = stl * 1024 + cl;   // st,c <= 512 each: fits
    #pragma unroll
    for (int off = 1; off < 64; off <<= 1) packed += __shfl_xor(packed, off);
    __shared__ int wred[3];
    if ((tid & 63) == 0) wred[tid >> 6] = packed;
    __syncthreads();
    const int tot = wred[0] + wred[1] + wred[2];
    const int st = tot >> 10;
    const int c  = tot & 1023;

    // ---- 8-wide masked accumulate: all loads independent, no serial tail ----
    const float4* hp = (const float4*)(hidden + ((size_t)b * L_ + st) * D_) + tid;
    const int stride = D_ / 4;  // 192
    float4 a0 = {0, 0, 0, 0}, a1 = a0, a2 = a0, a3 = a0;
    for (int l = 0; l < c; l += 8) {
      const int i1 = min(l + 1, c - 1), i2 = min(l + 2, c - 1);
      const int i3 = min(l + 3, c - 1), i4 = min(l + 4, c - 1);
      const int i5 = min(l + 5, c - 1), i6 = min(l + 6, c - 1);
      const int i7 = min(l + 7, c - 1);
      float4 v0 = hp[(size_t)l  * stride];
      float4 v1 = hp[(size_t)i1 * stride];
      float4 v2 = hp[(size_t)i2 * stride];
      float4 v3 = hp[(size_t)i3 * stride];
      float4 v4 = hp[(size_t)i4 * stride];
      float4 v5 = hp[(size_t)i5 * stride];
      float4 v6 = hp[(size_t)i6 * stride];
      float4 v7 = hp[(size_t)i7 * stride];
      const float m1 = (l + 1 < c) ? 1.0f : 0.0f;
      const float m2 = (l + 2 < c) ? 1.0f : 0.0f;
      const float m3 = (l + 3 < c) ? 1.0f : 0.0f;
      const float m4 = (l + 4 < c) ? 1.0f : 0.0f;
      const float m5 = (l + 5 < c) ? 1.0f : 0.0f;
      const float m6 = (l + 6 < c) ? 1.0f : 0.0f;
      const float m7 = (l + 7 < c) ? 1.0f : 0.0f;
      a0 = f4fma(a0, v0, 1.0f); a1 = f4fma(a1, v1, m1);
      a2 = f4fma(a2, v2, m2);   a3 = f4fma(a3, v3, m3);
      a0 = f4fma(a0, v4, m4);   a1 = f4fma(a1, v5, m5);
      a2 = f4fma(a2, v6, m6);   a3 = f4fma(a3, v7, m7);
    }
    a0.x += a1.x + a2.x + a3.x; a0.y += a1.y + a2.y + a3.y;
    a0.z += a1.z + a2.z + a3.z; a0.w += a1.w + a2.w + a3.w;

    const float inv = 1.0f / (float)max(c, 1);
    float o[4] = {a0.x * inv, a0.y * inv, a0.z * inv, a0.w * inv};
    ushort4 h, l4;
    h.x = f2h(o[0]); l4.x = f2h(o[0] - h2f(h.x));
    h.y = f2h(o[1]); l4.y = f2h(o[1] - h2f(h.y));
    h.z = f2h(o[2]); l4.z = f2h(o[2] - h2f(h.z));
    h.w = f2h(o[3]); l4.w = f2h(o[3] - h2f(h.w));
    const size_t idx = ((size_t)b * S_ + s) * D_ + tid * 4;
    *(ushort4*)&mh[idx] = h;
    *(ushort4*)&ml[idx] = l4;
  } else {
    // ---- weight transpose, single f16 (32x32 tiles, 192 threads) ----
    int wb = bid - M_;
    const float* W; ushort* Wt; int K, N, nblk, kblk;
    if (wb < 288) {  // W1: 12 col-tiles x 24 row-tiles
      W = W1; Wt = w1t; K = D_; N = N1_;
      nblk = wb % 12; kblk = wb / 12;
    } else {         // W2: 4 x 12
      wb -= 288;
      W = W2; Wt = w2t; K = N1_; N = N2_;
      nblk = wb % 4; kblk = wb / 4;
    }
    __shared__ float tile[32][33];
    const int n0 = nblk * 32, k0 = kblk * 32;
    const int tx = tid & 31, ty = tid >> 5;  // 32 x 6
    for (int r = ty; r < 32; r += 6)
      tile[r][tx] = W[(size_t)(k0 + r) * N + n0 + tx];
    __syncthreads();
    for (int r = ty; r < 32; r += 6)
      Wt[(size_t)(n0 + r) * K + k0 + tx] = f2h(tile[tx][r]);
  }
}

// ---------------------------------------------------------------------------
// Kernel 2: GEMM1 via MFMA f16, A hi/lo 2-pass, 8 waves with K-split.
// A: [M][K] f16 hi/lo. B: B^T [N][K] single f16.
// BK=64 per stage: waves 0-3 consume kk 0..31, waves 4-7 kk 32..63.
// Epilogue: waves 4-7 dump partial acc to LDS, waves 0-3 combine + store
// h1 as f16 hi/lo. Grid (N/64, M/64) = 384 blocks x 512 threads.
// ---------------------------------------------------------------------------
__global__ __launch_bounds__(512) void gemm_mfma8(
    const ushort* __restrict__ Ah, const ushort* __restrict__ Al,
    const ushort* __restrict__ Bs, const float* __restrict__ bias,
    ushort* __restrict__ Ch, ushort* __restrict__ Cl, int M, int N, int K) {
  constexpr int LDK = 72;  // 64 + 8 pad: frag-read rows 2-way alias only
  __shared__ __align__(16) ushort smem[3 * 64 * LDK];  // 27,648 B
  ushort* sAh = smem;
  ushort* sAl = smem + 64 * LDK;
  ushort* sB  = smem + 2 * 64 * LDK;

  const int tid  = threadIdx.x;
  const int wid  = tid >> 6;
  const int lane = tid & 63;
  const int w2 = wid & 3;
  const int kh = (wid >> 2) * 32;       // K-split: 0 or 32 within BK=64
  const int m0 = (w2 >> 1) * 32;
  const int n0 = (w2 & 1) * 32;
  const int lrow = lane & 15;
  const int lk   = (lane >> 4) * 8;

  const int srow = tid >> 3;            // 0..63
  const int sk   = (tid & 7) * 8;       // 0..56
  const int soff = srow * LDK + sk;

  const int brow = blockIdx.y * 64;
  const int bcol = blockIdx.x * 64;

  const ushort* Aph = Ah + (size_t)(brow + srow) * K + sk;
  const ushort* Apl = Al + (size_t)(brow + srow) * K + sk;
  const ushort* Bp  = Bs + (size_t)(bcol + srow) * K + sk;

  const int NT = K / 64;   // 12 for K=768

  uint4 ra_h = *(const uint4*)Aph;
  uint4 ra_l = *(const uint4*)Apl;
  uint4 rb   = *(const uint4*)Bp;

  f32x4 acc[2][2] = {};

  for (int t = 0; t < NT; ++t) {
    *(uint4*)&sAh[soff] = ra_h;
    *(uint4*)&sAl[soff] = ra_l;
    *(uint4*)&sB[soff]  = rb;
    __syncthreads();
    if (t + 1 < NT) {
      ra_h = *(const uint4*)(Aph + (size_t)(t + 1) * 64);
      ra_l = *(const uint4*)(Apl + (size_t)(t + 1) * 64);
      rb   = *(const uint4*)(Bp  + (size_t)(t + 1) * 64);
    }
    half8 ah[2], al[2], bb[2];
    #pragma unroll
    for (int i = 0; i < 2; ++i) {
      const int ro = (m0 + i * 16 + lrow) * LDK + kh + lk;
      ah[i] = *(const half8*)&sAh[ro];
      al[i] = *(const half8*)&sAl[ro];
    }
    #pragma unroll
    for (int j = 0; j < 2; ++j) {
      const int ro = (n0 + j * 16 + lrow) * LDK + kh + lk;
      bb[j] = *(const half8*)&sB[ro];
    }
    #pragma unroll
    for (int i = 0; i < 2; ++i)
      #pragma unroll
      for (int j = 0; j < 2; ++j) {
        acc[i][j] = __builtin_amdgcn_mfma_f32_16x16x32_f16(ah[i], bb[j], acc[i][j], 0, 0, 0);
        acc[i][j] = __builtin_amdgcn_mfma_f32_16x16x32_f16(al[i], bb[j], acc[i][j], 0, 0, 0);
      }
    __syncthreads();
  }

  // ---- combine K-split partials through LDS (stride 18 dwords: 2-way) ----
  float* red = (float*)smem;
  const int roff = (w2 * 64 + lane) * 18;
  if (wid >= 4) {
    #pragma unroll
    for (int i = 0; i < 2; ++i)
      #pragma unroll
      for (int j = 0; j < 2; ++j) {
        *(float2*)&red[roff + i * 8 + j * 4]     = make_float2(acc[i][j][0], acc[i][j][1]);
        *(float2*)&red[roff + i * 8 + j * 4 + 2] = make_float2(acc[i][j][2], acc[i][j][3]);
      }
  }
  __syncthreads();
  if (wid < 4) {
    #pragma unroll
    for (int i = 0; i < 2; ++i)
      #pragma unroll
      for (int j = 0; j < 2; ++j) {
        float2 p0 = *(float2*)&red[roff + i * 8 + j * 4];
        float2 p1 = *(float2*)&red[roff + i * 8 + j * 4 + 2];
        acc[i][j][0] += p0.x; acc[i][j][1] += p0.y;
        acc[i][j][2] += p1.x; acc[i][j][3] += p1.y;
        const float bj = bias[bcol + n0 + j * 16 + lrow];
        #pragma unroll
        for (int r = 0; r < 4; ++r) {
          float v = fmaxf(acc[i][j][r] + bj, 0.0f);
          const size_t idx =
              (size_t)(brow + m0 + i * 16 + (lane >> 4) * 4 + r) * N +
              bcol + n0 + j * 16 + lrow;
          ushort h = f2h(v);
          Ch[idx] = h;
          Cl[idx] = f2h(v - h2f(h));
        }
      }
  }
}

// ---------------------------------------------------------------------------
// Kernel 3: GEMM2 (h1 @ W2 + b2, relu) fused with final (@ W3 + b3).
// A hi/lo f16 2-pass, B single f16. BM=32, BN=128 (full N2): 128 blocks,
// 4 waves each own a 32-col slice; h2 tile stays f32 in registers;
// epilogue reduces x W3 via shfl + LDS atomics.
// ---------------------------------------------------------------------------
__global__ __launch_bounds__(256) void gemm2_final(
    const ushort* __restrict__ Ah, const ushort* __restrict__ Al,
    const ushort* __restrict__ Bs, const float* __restrict__ b2,
    const float* __restrict__ W3, const float* __restrict__ b3,
    float* __restrict__ out) {
  constexpr int K = N1_;   // 384
  constexpr int LDA = 40;
  __shared__ __align__(16) ushort sA[2][2][32 * LDA];    // [buf][hi/lo]
  __shared__ __align__(16) ushort sB[2][128 * LDA];
  __shared__ float pl[32][2];

  const int tid  = threadIdx.x;
  const int wid  = tid >> 6;
  const int lane = tid & 63;
  const int n0 = wid * 32;          // wave's 32-col slice of N2=128
  const int lrow = lane & 15;
  const int lk   = (lane >> 4) * 8;
  const int brow = blockIdx.x * 32;

  // A staging: 32 rows x 32 k; threads 0..127 -> hi, 128..255 -> lo
  const int t7  = tid & 127;
  const int srA = t7 >> 2, skA = (t7 & 3) * 8;
  const ushort* pA = ((tid < 128) ? Ah : Al) + (size_t)(brow + srA) * K + skA;
  const int offA = srA * LDA + skA;
  const int abuf = (tid < 128) ? 0 : 1;
  // B staging: 128 rows x 32 k f16; each thread 2 uint4
  const int srB = tid >> 1, skB = (tid & 1) * 16;
  const ushort* pB = Bs + (size_t)srB * K + skB;
  const int offB = srB * LDA + skB;

  uint4 ra  = *(const uint4*)pA;
  uint4 rb0 = *(const uint4*)pB;
  uint4 rb1 = *(const uint4*)(pB + 8);
  *(uint4*)&sA[0][abuf][offA] = ra;
  *(uint4*)&sB[0][offB] = rb0;
  *(uint4*)&sB[0][offB + 8] = rb1;
  __syncthreads();

  f32x4 acc[2][2] = {};   // i: 2 row-frags (32 rows), j: 2 col-frags (32 cols)
  constexpr int NT = K / 32;  // 12

  for (int t = 0; t < NT; ++t) {
    const int cur = t & 1;
    if (t + 1 < NT) {
      ra  = *(const uint4*)(pA + (size_t)(t + 1) * 32);
      rb0 = *(const uint4*)(pB + (size_t)(t + 1) * 32);
      rb1 = *(const uint4*)(pB + (size_t)(t + 1) * 32 + 8);
    }
    half8 ah[2], al[2], bb[2];
    #pragma unroll
    for (int i = 0; i < 2; ++i) {
      const int ro = (i * 16 + lrow) * LDA + lk;
      ah[i] = *(const half8*)&sA[cur][0][ro];
      al[i] = *(const half8*)&sA[cur][1][ro];
    }
    #pragma unroll
    for (int j = 0; j < 2; ++j) {
      const int ro = (n0 + j * 16 + lrow) * LDA + lk;
      bb[j] = *(const half8*)&sB[cur][ro];
    }
    #pragma unroll
    for (int i = 0; i < 2; ++i)
      #pragma unroll
      for (int j = 0; j < 2; ++j) {
        acc[i][j] = __builtin_amdgcn_mfma_f32_16x16x32_f16(ah[i], bb[j], acc[i][j], 0, 0, 0);
        acc[i][j] = __builtin_amdgcn_mfma_f32_16x16x32_f16(al[i], bb[j], acc[i][j], 0, 0, 0);
      }
    if (t + 1 < NT) {
      __syncthreads();
      const int nxt = cur ^ 1;
      *(uint4*)&sA[nxt][abuf][offA] = ra;
      *(uint4*)&sB[nxt][offB] = rb0;
      *(uint4*)&sB[nxt][offB + 8] = rb1;
      __syncthreads();
    }
  }

  // ---- fused epilogue: h2 = relu(acc + b2); logits = h2 @ W3 + b3 ----
  __syncthreads();
  if (tid < 64) pl[tid >> 1][tid & 1] = 0.0f;
  float w3v[2][2], b2v[2];
  #pragma unroll
  for (int j = 0; j < 2; ++j) {
    const int col = n0 + j * 16 + lrow;
    w3v[j][0] = W3[col * 2 + 0];
    w3v[j][1] = W3[col * 2 + 1];
    b2v[j] = b2[col];
  }
  __syncthreads();
  #pragma unroll
  for (int i = 0; i < 2; ++i)
    #pragma unroll
    for (int r = 0; r < 4; ++r) {
      float p0 = 0.0f, p1 = 0.0f;
      #pragma unroll
      for (int j = 0; j < 2; ++j) {
        float v = fmaxf(acc[i][j][r] + b2v[j], 0.0f);
        p0 += v * w3v[j][0];
        p1 += v * w3v[j][1];
      }
      p0 += __shfl_xor(p0, 1); p1 += __shfl_xor(p1, 1);
      p0 += __shfl_xor(p0, 2); p1 += __shfl_xor(p1, 2);
      p0 += __shfl_xor(p0, 4); p1 += __shfl_xor(p1, 4);
      p0 += __shfl_xor(p0, 8); p1 += __shfl_xor(p1, 8);
      if (lrow == 0) {
        const int row = i * 16 + (lane >> 4) * 4 + r;
        atomicAdd(&pl[row][0], p0);
        atomicAdd(&pl[row][1], p1);
      }
    }
  __syncthreads();
  if (tid < 64) {
    const int row = tid >> 1, c = tid & 1;
    out[(size_t)(brow + row) * 2 + c] = pl[row][c] + b3[c];
  }
}

// ---------------------------------------------------------------------------
extern "C" void kernel_launch(void* const* d_in, const int* in_sizes, int n_in,
                              void* d_out, int out_size, void* d_ws, size_t ws_size,
                              hipStream_t stream) {
  const float* hidden  = (const float*)d_in[0];
  const int*   seg_ids = (const int*)d_in[1];
  const float* W1 = (const float*)d_in[2];
  const float* b1 = (const float*)d_in[3];
  const float* W2 = (const float*)d_in[4];
  const float* b2 = (const float*)d_in[5];
  const float* W3 = (const float*)d_in[6];
  const float* b3 = (const float*)d_in[7];
  float* out = (float*)d_out;

  // workspace layout (all 16B-aligned)
  char* p = (char*)d_ws;
  ushort* mh  = (ushort*)p;  p += (size_t)M_ * D_ * 2;     // f16 hi
  ushort* ml  = (ushort*)p;  p += (size_t)M_ * D_ * 2;     // f16 lo
  ushort* w1t = (ushort*)p;  p += (size_t)N1_ * D_ * 2;    // f16 single
  ushort* h1h = (ushort*)p;  p += (size_t)M_ * N1_ * 2;
  ushort* h1l = (ushort*)p;  p += (size_t)M_ * N1_ * 2;
  ushort* w2t = (ushort*)p;  p += (size_t)N2_ * N1_ * 2;

  mean_prep_kernel<<<M_ + 288 + 48, 192, 0, stream>>>(
      hidden, seg_ids, mh, ml, W1, w1t, W2, w2t);
  gemm_mfma8<<<dim3(N1_ / 64, M_ / 64), 512, 0, stream>>>(
      mh, ml, w1t, b1, h1h, h1l, M_, N1_, D_);
  gemm2_final<<<M_ / 32, 256, 0, stream>>>(
      h1h, h1l, w2t, b2, W3, b3, out);
}

// Round 8
// 41.238 us; speedup vs baseline: 3.6977x; 1.1599x over previous
//
#include <hip/hip_runtime.h>
#include <hip/hip_fp16.h>

#define B_  64
#define L_  512
#define D_  768
#define S_  64
#define M_  (B_ * S_)   // 4096 output rows
#define N1_ 384
#define N2_ 128

typedef __attribute__((ext_vector_type(8))) _Float16 half8;
typedef __attribute__((ext_vector_type(4))) float f32x4;

__device__ __forceinline__ ushort f2h(float x) {
  return __half_as_ushort(__float2half_rn(x));
}
__device__ __forceinline__ float4 f4fma(float4 a, float4 v, float m) {
  return make_float4(fmaf(v.x, m, a.x), fmaf(v.y, m, a.y),
                     fmaf(v.z, m, a.z), fmaf(v.w, m, a.w));
}

// ---------------------------------------------------------------------------
// Kernel 1 (one launch): blocks 0..4095 -> segment mean for (s,b) incl. its
// own bounds scan (register-only + shfl), output = single f16;
// blocks 4096.. -> weight transpose to B^T layout, single f16.
// ---------------------------------------------------------------------------
__global__ __launch_bounds__(192) void mean_prep_kernel(
    const float* __restrict__ hidden, const int* __restrict__ seg_ids,
    ushort* __restrict__ mh,
    const float* __restrict__ W1, ushort* __restrict__ w1t,
    const float* __restrict__ W2, ushort* __restrict__ w2t) {
  const int bid = blockIdx.x;
  const int tid = threadIdx.x;

  if (bid < M_) {
    // ---- bounds scan: 128 threads each load one int4, count in regs ----
    const int s = bid & 63;
    const int b = bid >> 6;
    int stl = 0, cl = 0;
    if (tid < 128) {
      int4 v = ((const int4*)(seg_ids + b * L_))[tid];
      stl = (v.x < s) + (v.y < s) + (v.z < s) + (v.w < s);
      cl  = (v.x == s) + (v.y == s) + (v.z == s) + (v.w == s);
    }
    int packed = stl * 1024 + cl;   // st,c <= 512 each: fits
    #pragma unroll
    for (int off = 1; off < 64; off <<= 1) packed += __shfl_xor(packed, off);
    __shared__ int wred[3];
    if ((tid & 63) == 0) wred[tid >> 6] = packed;
    __syncthreads();
    const int tot = wred[0] + wred[1] + wred[2];
    const int st = tot >> 10;
    const int c  = tot & 1023;

    // ---- 8-wide masked accumulate: all loads independent, no serial tail ----
    const float4* hp = (const float4*)(hidden + ((size_t)b * L_ + st) * D_) + tid;
    const int stride = D_ / 4;  // 192
    float4 a0 = {0, 0, 0, 0}, a1 = a0, a2 = a0, a3 = a0;
    for (int l = 0; l < c; l += 8) {
      const int i1 = min(l + 1, c - 1), i2 = min(l + 2, c - 1);
      const int i3 = min(l + 3, c - 1), i4 = min(l + 4, c - 1);
      const int i5 = min(l + 5, c - 1), i6 = min(l + 6, c - 1);
      const int i7 = min(l + 7, c - 1);
      float4 v0 = hp[(size_t)l  * stride];
      float4 v1 = hp[(size_t)i1 * stride];
      float4 v2 = hp[(size_t)i2 * stride];
      float4 v3 = hp[(size_t)i3 * stride];
      float4 v4 = hp[(size_t)i4 * stride];
      float4 v5 = hp[(size_t)i5 * stride];
      float4 v6 = hp[(size_t)i6 * stride];
      float4 v7 = hp[(size_t)i7 * stride];
      const float m1 = (l + 1 < c) ? 1.0f : 0.0f;
      const float m2 = (l + 2 < c) ? 1.0f : 0.0f;
      const float m3 = (l + 3 < c) ? 1.0f : 0.0f;
      const float m4 = (l + 4 < c) ? 1.0f : 0.0f;
      const float m5 = (l + 5 < c) ? 1.0f : 0.0f;
      const float m6 = (l + 6 < c) ? 1.0f : 0.0f;
      const float m7 = (l + 7 < c) ? 1.0f : 0.0f;
      a0 = f4fma(a0, v0, 1.0f); a1 = f4fma(a1, v1, m1);
      a2 = f4fma(a2, v2, m2);   a3 = f4fma(a3, v3, m3);
      a0 = f4fma(a0, v4, m4);   a1 = f4fma(a1, v5, m5);
      a2 = f4fma(a2, v6, m6);   a3 = f4fma(a3, v7, m7);
    }
    a0.x += a1.x + a2.x + a3.x; a0.y += a1.y + a2.y + a3.y;
    a0.z += a1.z + a2.z + a3.z; a0.w += a1.w + a2.w + a3.w;

    const float inv = 1.0f / (float)max(c, 1);
    ushort4 h;
    h.x = f2h(a0.x * inv);
    h.y = f2h(a0.y * inv);
    h.z = f2h(a0.z * inv);
    h.w = f2h(a0.w * inv);
    const size_t idx = ((size_t)b * S_ + s) * D_ + tid * 4;
    *(ushort4*)&mh[idx] = h;
  } else {
    // ---- weight transpose, single f16 (32x32 tiles, 192 threads) ----
    int wb = bid - M_;
    const float* W; ushort* Wt; int K, N, nblk, kblk;
    if (wb < 288) {  // W1: 12 col-tiles x 24 row-tiles
      W = W1; Wt = w1t; K = D_; N = N1_;
      nblk = wb % 12; kblk = wb / 12;
    } else {         // W2: 4 x 12
      wb -= 288;
      W = W2; Wt = w2t; K = N1_; N = N2_;
      nblk = wb % 4; kblk = wb / 4;
    }
    __shared__ float tile[32][33];
    const int n0 = nblk * 32, k0 = kblk * 32;
    const int tx = tid & 31, ty = tid >> 5;  // 32 x 6
    for (int r = ty; r < 32; r += 6)
      tile[r][tx] = W[(size_t)(k0 + r) * N + n0 + tx];
    __syncthreads();
    for (int r = ty; r < 32; r += 6)
      Wt[(size_t)(n0 + r) * K + k0 + tx] = f2h(tile[tx][r]);
  }
}

// ---------------------------------------------------------------------------
// Kernel 2: GEMM1 via MFMA f16 single-pass, 8 waves with K-split.
// A: [M][K] f16. B: B^T [N][K] f16. C = relu(A@B + bias) -> f16.
// BK=64 per stage: waves 0-3 consume kk 0..31, waves 4-7 kk 32..63.
// Epilogue: waves 4-7 dump partial acc to LDS, waves 0-3 combine + store.
// Grid (N/64, M/64) = 384 blocks x 512 threads.
// ---------------------------------------------------------------------------
__global__ __launch_bounds__(512) void gemm_mfma8(
    const ushort* __restrict__ As, const ushort* __restrict__ Bs,
    const float* __restrict__ bias, ushort* __restrict__ Cs,
    int M, int N, int K) {
  constexpr int LDK = 72;  // 64 + 8 pad: frag-read rows 2-way alias only
  __shared__ __align__(16) ushort smem[2 * 64 * LDK];  // 18,432 B
  ushort* sA = smem;
  ushort* sB = smem + 64 * LDK;

  const int tid  = threadIdx.x;
  const int wid  = tid >> 6;
  const int lane = tid & 63;
  const int w2 = wid & 3;
  const int kh = (wid >> 2) * 32;       // K-split: 0 or 32 within BK=64
  const int m0 = (w2 >> 1) * 32;
  const int n0 = (w2 & 1) * 32;
  const int lrow = lane & 15;
  const int lk   = (lane >> 4) * 8;

  // staging: 512 threads cover A(64x64) + B(64x64) halves: tid<256 -> A rows,
  // tid>=256 -> B rows; each thread one uint4 (8 f16).
  const int half = tid >> 8;            // 0: A, 1: B
  const int t8   = tid & 255;
  const int srow = t8 >> 2;             // 0..63
  const int sk   = (t8 & 3) * 16;       // 0,16,32,48
  const int soff = srow * LDK + sk;

  const int brow = blockIdx.y * 64;
  const int bcol = blockIdx.x * 64;

  const ushort* gp = half ? (Bs + (size_t)(bcol + srow) * K + sk)
                          : (As + (size_t)(brow + srow) * K + sk);
  ushort* sp = half ? sB : sA;

  const int NT = K / 64;   // 12 for K=768

  uint4 r0 = *(const uint4*)gp;
  uint4 r1 = *(const uint4*)(gp + 8);

  f32x4 acc[2][2] = {};

  for (int t = 0; t < NT; ++t) {
    *(uint4*)&sp[soff]     = r0;
    *(uint4*)&sp[soff + 8] = r1;
    __syncthreads();
    if (t + 1 < NT) {
      r0 = *(const uint4*)(gp + (size_t)(t + 1) * 64);
      r1 = *(const uint4*)(gp + (size_t)(t + 1) * 64 + 8);
    }
    half8 av[2], bv[2];
    #pragma unroll
    for (int i = 0; i < 2; ++i) {
      av[i] = *(const half8*)&sA[(m0 + i * 16 + lrow) * LDK + kh + lk];
      bv[i] = *(const half8*)&sB[(n0 + i * 16 + lrow) * LDK + kh + lk];
    }
    #pragma unroll
    for (int i = 0; i < 2; ++i)
      #pragma unroll
      for (int j = 0; j < 2; ++j)
        acc[i][j] = __builtin_amdgcn_mfma_f32_16x16x32_f16(av[i], bv[j], acc[i][j], 0, 0, 0);
    __syncthreads();
  }

  // ---- combine K-split partials through LDS (stride 18 dwords: 2-way) ----
  float* red = (float*)smem;
  const int roff = (w2 * 64 + lane) * 18;
  if (wid >= 4) {
    #pragma unroll
    for (int i = 0; i < 2; ++i)
      #pragma unroll
      for (int j = 0; j < 2; ++j) {
        *(float2*)&red[roff + i * 8 + j * 4]     = make_float2(acc[i][j][0], acc[i][j][1]);
        *(float2*)&red[roff + i * 8 + j * 4 + 2] = make_float2(acc[i][j][2], acc[i][j][3]);
      }
  }
  __syncthreads();
  if (wid < 4) {
    #pragma unroll
    for (int i = 0; i < 2; ++i)
      #pragma unroll
      for (int j = 0; j < 2; ++j) {
        float2 p0 = *(float2*)&red[roff + i * 8 + j * 4];
        float2 p1 = *(float2*)&red[roff + i * 8 + j * 4 + 2];
        acc[i][j][0] += p0.x; acc[i][j][1] += p0.y;
        acc[i][j][2] += p1.x; acc[i][j][3] += p1.y;
        const float bj = bias[bcol + n0 + j * 16 + lrow];
        #pragma unroll
        for (int r = 0; r < 4; ++r) {
          float v = fmaxf(acc[i][j][r] + bj, 0.0f);
          const size_t idx =
              (size_t)(brow + m0 + i * 16 + (lane >> 4) * 4 + r) * N +
              bcol + n0 + j * 16 + lrow;
          Cs[idx] = f2h(v);
        }
      }
  }
}

// ---------------------------------------------------------------------------
// Kernel 3: GEMM2 (h1 @ W2 + b2, relu) fused with final (@ W3 + b3).
// Single f16. BM=32, BN=128 (full N2): 128 blocks, 4 waves each own a
// 32-col slice; h2 tile stays f32 in registers; epilogue reduces x W3 via
// shfl + LDS atomics.
// ---------------------------------------------------------------------------
__global__ __launch_bounds__(256) void gemm2_final(
    const ushort* __restrict__ As, const ushort* __restrict__ Bs,
    const float* __restrict__ b2, const float* __restrict__ W3,
    const float* __restrict__ b3, float* __restrict__ out) {
  constexpr int K = N1_;   // 384
  constexpr int LDA = 40;
  __shared__ __align__(16) ushort sA[2][32 * LDA];
  __shared__ __align__(16) ushort sB[2][128 * LDA];
  __shared__ float pl[32][2];

  const int tid  = threadIdx.x;
  const int wid  = tid >> 6;
  const int lane = tid & 63;
  const int n0 = wid * 32;          // wave's 32-col slice of N2=128
  const int lrow = lane & 15;
  const int lk   = (lane >> 4) * 8;
  const int brow = blockIdx.x * 32;

  // A staging: 32 rows x 32 k by threads 0..127 (uint4 each)
  const int t7  = tid & 127;
  const int srA = t7 >> 2, skA = (t7 & 3) * 8;
  const ushort* pA = As + (size_t)(brow + srA) * K + skA;
  const int offA = srA * LDA + skA;
  // B staging: 128 rows x 32 k f16; each thread 2 uint4
  const int srB = tid >> 1, skB = (tid & 1) * 16;
  const ushort* pB = Bs + (size_t)srB * K + skB;
  const int offB = srB * LDA + skB;

  uint4 ra = {0, 0, 0, 0};
  if (tid < 128) ra = *(const uint4*)pA;
  uint4 rb0 = *(const uint4*)pB;
  uint4 rb1 = *(const uint4*)(pB + 8);
  if (tid < 128) *(uint4*)&sA[0][offA] = ra;
  *(uint4*)&sB[0][offB] = rb0;
  *(uint4*)&sB[0][offB + 8] = rb1;
  __syncthreads();

  f32x4 acc[2][2] = {};   // i: 2 row-frags (32 rows), j: 2 col-frags (32 cols)
  constexpr int NT = K / 32;  // 12

  for (int t = 0; t < NT; ++t) {
    const int cur = t & 1;
    if (t + 1 < NT) {
      if (tid < 128) ra = *(const uint4*)(pA + (size_t)(t + 1) * 32);
      rb0 = *(const uint4*)(pB + (size_t)(t + 1) * 32);
      rb1 = *(const uint4*)(pB + (size_t)(t + 1) * 32 + 8);
    }
    half8 av[2], bv[2];
    #pragma unroll
    for (int i = 0; i < 2; ++i)
      av[i] = *(const half8*)&sA[cur][(i * 16 + lrow) * LDA + lk];
    #pragma unroll
    for (int j = 0; j < 2; ++j)
      bv[j] = *(const half8*)&sB[cur][(n0 + j * 16 + lrow) * LDA + lk];
    #pragma unroll
    for (int i = 0; i < 2; ++i)
      #pragma unroll
      for (int j = 0; j < 2; ++j)
        acc[i][j] = __builtin_amdgcn_mfma_f32_16x16x32_f16(av[i], bv[j], acc[i][j], 0, 0, 0);
    if (t + 1 < NT) {
      __syncthreads();
      const int nxt = cur ^ 1;
      if (tid < 128) *(uint4*)&sA[nxt][offA] = ra;
      *(uint4*)&sB[nxt][offB] = rb0;
      *(uint4*)&sB[nxt][offB + 8] = rb1;
      __syncthreads();
    }
  }

  // ---- fused epilogue: h2 = relu(acc + b2); logits = h2 @ W3 + b3 ----
  __syncthreads();
  if (tid < 64) pl[tid >> 1][tid & 1] = 0.0f;
  float w3v[2][2], b2v[2];
  #pragma unroll
  for (int j = 0; j < 2; ++j) {
    const int col = n0 + j * 16 + lrow;
    w3v[j][0] = W3[col * 2 + 0];
    w3v[j][1] = W3[col * 2 + 1];
    b2v[j] = b2[col];
  }
  __syncthreads();
  #pragma unroll
  for (int i = 0; i < 2; ++i)
    #pragma unroll
    for (int r = 0; r < 4; ++r) {
      float p0 = 0.0f, p1 = 0.0f;
      #pragma unroll
      for (int j = 0; j < 2; ++j) {
        float v = fmaxf(acc[i][j][r] + b2v[j], 0.0f);
        p0 += v * w3v[j][0];
        p1 += v * w3v[j][1];
      }
      p0 += __shfl_xor(p0, 1); p1 += __shfl_xor(p1, 1);
      p0 += __shfl_xor(p0, 2); p1 += __shfl_xor(p1, 2);
      p0 += __shfl_xor(p0, 4); p1 += __shfl_xor(p1, 4);
      p0 += __shfl_xor(p0, 8); p1 += __shfl_xor(p1, 8);
      if (lrow == 0) {
        const int row = i * 16 + (lane >> 4) * 4 + r;
        atomicAdd(&pl[row][0], p0);
        atomicAdd(&pl[row][1], p1);
      }
    }
  __syncthreads();
  if (tid < 64) {
    const int row = tid >> 1, c = tid & 1;
    out[(size_t)(brow + row) * 2 + c] = pl[row][c] + b3[c];
  }
}

// ---------------------------------------------------------------------------
extern "C" void kernel_launch(void* const* d_in, const int* in_sizes, int n_in,
                              void* d_out, int out_size, void* d_ws, size_t ws_size,
                              hipStream_t stream) {
  const float* hidden  = (const float*)d_in[0];
  const int*   seg_ids = (const int*)d_in[1];
  const float* W1 = (const float*)d_in[2];
  const float* b1 = (const float*)d_in[3];
  const float* W2 = (const float*)d_in[4];
  const float* b2 = (const float*)d_in[5];
  const float* W3 = (const float*)d_in[6];
  const float* b3 = (const float*)d_in[7];
  float* out = (float*)d_out;

  // workspace layout (all 16B-aligned)
  char* p = (char*)d_ws;
  ushort* mh  = (ushort*)p;  p += (size_t)M_ * D_ * 2;     // means f16
  ushort* w1t = (ushort*)p;  p += (size_t)N1_ * D_ * 2;    // W1^T f16
  ushort* h1  = (ushort*)p;  p += (size_t)M_ * N1_ * 2;    // h1 f16
  ushort* w2t = (ushort*)p;  p += (size_t)N2_ * N1_ * 2;   // W2^T f16

  mean_prep_kernel<<<M_ + 288 + 48, 192, 0, stream>>>(
      hidden, seg_ids, mh, W1, w1t, W2, w2t);
  gemm_mfma8<<<dim3(N1_ / 64, M_ / 64), 512, 0, stream>>>(
      mh, w1t, b1, h1, M_, N1_, D_);
  gemm2_final<<<M_ / 32, 256, 0, stream>>>(
      h1, w2t, b2, W3, b3, out);
}

// Round 9
// 41.017 us; speedup vs baseline: 3.7176x; 1.0054x over previous
//
#include <hip/hip_runtime.h>
#include <hip/hip_fp16.h>

#define B_  64
#define L_  512
#define D_  768
#define S_  64
#define M_  (B_ * S_)   // 4096 output rows
#define N1_ 384
#define N2_ 128
#define SEG_C 4               // segments per mean block
#define NMB (M_ / SEG_C)      // 1024 mean blocks

typedef __attribute__((ext_vector_type(8))) _Float16 half8;
typedef __attribute__((ext_vector_type(4))) float f32x4;

__device__ __forceinline__ ushort f2h(float x) {
  return __half_as_ushort(__float2half_rn(x));
}

// ---------------------------------------------------------------------------
// Kernel 1 (one launch):
//  blocks 0..1023: streaming segment-mean over a (sample, 4-segment) chunk.
//    One bounds scan -> contiguous token span [lo,hi); stream rows with
//    batched 8-wide loads; flush per-segment mean at uniform boundaries.
//  blocks 1024.. : weight transpose to B^T layout, single f16.
// ---------------------------------------------------------------------------
__global__ __launch_bounds__(192) void mean_prep_kernel(
    const float* __restrict__ hidden, const int* __restrict__ seg_ids,
    ushort* __restrict__ mh,
    const float* __restrict__ W1, ushort* __restrict__ w1t,
    const float* __restrict__ W2, ushort* __restrict__ w2t) {
  const int bid = blockIdx.x;
  const int tid = threadIdx.x;

  if (bid < NMB) {
    const int b  = bid >> 4;
    const int s0 = (bid & 15) * SEG_C;
    __shared__ int sids[L_];
    __shared__ int wred[3];
    int pk = 0;
    if (tid < 128) {
      int4 v = ((const int4*)(seg_ids + b * L_))[tid];
      ((int4*)sids)[tid] = v;
      int clo = (v.x < s0) + (v.y < s0) + (v.z < s0) + (v.w < s0);
      int chi = (v.x < s0 + SEG_C) + (v.y < s0 + SEG_C) +
                (v.z < s0 + SEG_C) + (v.w < s0 + SEG_C);
      pk = clo * 1024 + chi;   // both <= 512: no carry between fields
    }
    #pragma unroll
    for (int off = 1; off < 64; off <<= 1) pk += __shfl_xor(pk, off);
    if ((tid & 63) == 0) wred[tid >> 6] = pk;
    __syncthreads();
    const int tot = wred[0] + wred[1] + wred[2];
    const int lo = tot >> 10;
    const int hi = tot & 1023;

    const float4* hp = (const float4*)(hidden + (size_t)b * L_ * D_) + tid;
    ushort* outb = mh + (size_t)b * S_ * D_ + tid * 4;  // row stride D_
    const uint2 zz = {0u, 0u};

    int cur = (lo < hi) ? sids[lo] : s0 + SEG_C;
    for (int z = s0; z < cur; ++z)          // leading empty segments
      *(uint2*)(outb + (size_t)z * D_) = zz;

    float4 acc = {0.0f, 0.0f, 0.0f, 0.0f};
    int segstart = lo;
    for (int l = lo; l < hi; l += 8) {
      float4 v[8];
      int sv[8];
      #pragma unroll
      for (int k = 0; k < 8; ++k) {
        v[k]  = hp[(size_t)min(l + k, hi - 1) * (D_ / 4)];
        sv[k] = sids[min(l + k + 1, hi - 1)];
      }
      #pragma unroll
      for (int k = 0; k < 8; ++k) {
        if (l + k < hi) {      // uniform
          acc.x += v[k].x; acc.y += v[k].y;
          acc.z += v[k].z; acc.w += v[k].w;
          const int nx = l + k + 1;
          if (nx == hi || sv[k] != cur) {   // uniform flush
            const float inv = 1.0f / (float)(nx - segstart);
            ushort4 h;
            h.x = f2h(acc.x * inv); h.y = f2h(acc.y * inv);
            h.z = f2h(acc.z * inv); h.w = f2h(acc.w * inv);
            *(ushort4*)(outb + (size_t)cur * D_) = h;
            const int nxt = (nx == hi) ? s0 + SEG_C : sv[k];
            for (int z = cur + 1; z < nxt; ++z)   // interior/trailing empties
              *(uint2*)(outb + (size_t)z * D_) = zz;
            acc.x = 0.0f; acc.y = 0.0f; acc.z = 0.0f; acc.w = 0.0f;
            segstart = nx; cur = nxt;
          }
        }
      }
    }
  } else {
    // ---- weight transpose, single f16 (32x32 tiles, 192 threads) ----
    int wb = bid - NMB;
    const float* W; ushort* Wt; int K, N, nblk, kblk;
    if (wb < 288) {  // W1: 12 col-tiles x 24 row-tiles
      W = W1; Wt = w1t; K = D_; N = N1_;
      nblk = wb % 12; kblk = wb / 12;
    } else {         // W2: 4 x 12
      wb -= 288;
      W = W2; Wt = w2t; K = N1_; N = N2_;
      nblk = wb % 4; kblk = wb / 4;
    }
    __shared__ float tile[32][33];
    const int n0 = nblk * 32, k0 = kblk * 32;
    const int tx = tid & 31, ty = tid >> 5;  // 32 x 6
    for (int r = ty; r < 32; r += 6)
      tile[r][tx] = W[(size_t)(k0 + r) * N + n0 + tx];
    __syncthreads();
    for (int r = ty; r < 32; r += 6)
      Wt[(size_t)(n0 + r) * K + k0 + tx] = f2h(tile[tx][r]);
  }
}

// ---------------------------------------------------------------------------
// Kernel 2: GEMM1 via MFMA f16 single-pass, 8 waves with K-split.
// A: [M][K] f16. B: B^T [N][K] f16. C = relu(A@B + bias) -> f16.
// BK=64 per stage: waves 0-3 consume kk 0..31, waves 4-7 kk 32..63.
// Epilogue: waves 4-7 dump partial acc to LDS, waves 0-3 combine + store.
// Grid (N/64, M/64) = 384 blocks x 512 threads.
// ---------------------------------------------------------------------------
__global__ __launch_bounds__(512) void gemm_mfma8(
    const ushort* __restrict__ As, const ushort* __restrict__ Bs,
    const float* __restrict__ bias, ushort* __restrict__ Cs,
    int M, int N, int K) {
  constexpr int LDK = 72;  // 64 + 8 pad: frag-read rows 2-way alias only
  __shared__ __align__(16) ushort smem[2 * 64 * LDK];  // 18,432 B
  ushort* sA = smem;
  ushort* sB = smem + 64 * LDK;

  const int tid  = threadIdx.x;
  const int wid  = tid >> 6;
  const int lane = tid & 63;
  const int w2 = wid & 3;
  const int kh = (wid >> 2) * 32;       // K-split: 0 or 32 within BK=64
  const int m0 = (w2 >> 1) * 32;
  const int n0 = (w2 & 1) * 32;
  const int lrow = lane & 15;
  const int lk   = (lane >> 4) * 8;

  // staging: tid<256 -> A rows, tid>=256 -> B rows; one uint4 pair each.
  const int half = tid >> 8;            // 0: A, 1: B
  const int t8   = tid & 255;
  const int srow = t8 >> 2;             // 0..63
  const int sk   = (t8 & 3) * 16;       // 0,16,32,48
  const int soff = srow * LDK + sk;

  const int brow = blockIdx.y * 64;
  const int bcol = blockIdx.x * 64;

  const ushort* gp = half ? (Bs + (size_t)(bcol + srow) * K + sk)
                          : (As + (size_t)(brow + srow) * K + sk);
  ushort* sp = half ? sB : sA;

  const int NT = K / 64;   // 12 for K=768

  uint4 r0 = *(const uint4*)gp;
  uint4 r1 = *(const uint4*)(gp + 8);

  f32x4 acc[2][2] = {};

  for (int t = 0; t < NT; ++t) {
    *(uint4*)&sp[soff]     = r0;
    *(uint4*)&sp[soff + 8] = r1;
    __syncthreads();
    if (t + 1 < NT) {
      r0 = *(const uint4*)(gp + (size_t)(t + 1) * 64);
      r1 = *(const uint4*)(gp + (size_t)(t + 1) * 64 + 8);
    }
    half8 av[2], bv[2];
    #pragma unroll
    for (int i = 0; i < 2; ++i) {
      av[i] = *(const half8*)&sA[(m0 + i * 16 + lrow) * LDK + kh + lk];
      bv[i] = *(const half8*)&sB[(n0 + i * 16 + lrow) * LDK + kh + lk];
    }
    #pragma unroll
    for (int i = 0; i < 2; ++i)
      #pragma unroll
      for (int j = 0; j < 2; ++j)
        acc[i][j] = __builtin_amdgcn_mfma_f32_16x16x32_f16(av[i], bv[j], acc[i][j], 0, 0, 0);
    __syncthreads();
  }

  // ---- combine K-split partials through LDS (stride 18 dwords: 2-way) ----
  float* red = (float*)smem;
  const int roff = (w2 * 64 + lane) * 18;
  if (wid >= 4) {
    #pragma unroll
    for (int i = 0; i < 2; ++i)
      #pragma unroll
      for (int j = 0; j < 2; ++j) {
        *(float2*)&red[roff + i * 8 + j * 4]     = make_float2(acc[i][j][0], acc[i][j][1]);
        *(float2*)&red[roff + i * 8 + j * 4 + 2] = make_float2(acc[i][j][2], acc[i][j][3]);
      }
  }
  __syncthreads();
  if (wid < 4) {
    #pragma unroll
    for (int i = 0; i < 2; ++i)
      #pragma unroll
      for (int j = 0; j < 2; ++j) {
        float2 p0 = *(float2*)&red[roff + i * 8 + j * 4];
        float2 p1 = *(float2*)&red[roff + i * 8 + j * 4 + 2];
        acc[i][j][0] += p0.x; acc[i][j][1] += p0.y;
        acc[i][j][2] += p1.x; acc[i][j][3] += p1.y;
        const float bj = bias[bcol + n0 + j * 16 + lrow];
        #pragma unroll
        for (int r = 0; r < 4; ++r) {
          float v = fmaxf(acc[i][j][r] + bj, 0.0f);
          const size_t idx =
              (size_t)(brow + m0 + i * 16 + (lane >> 4) * 4 + r) * N +
              bcol + n0 + j * 16 + lrow;
          Cs[idx] = f2h(v);
        }
      }
  }
}

// ---------------------------------------------------------------------------
// Kernel 3: GEMM2 (h1 @ W2 + b2, relu) fused with final (@ W3 + b3).
// Single f16. BM=32, BN=128 (full N2): 128 blocks, 4 waves each own a
// 32-col slice; h2 tile stays f32 in registers; epilogue reduces x W3 via
// shfl + LDS atomics.
// ---------------------------------------------------------------------------
__global__ __launch_bounds__(256) void gemm2_final(
    const ushort* __restrict__ As, const ushort* __restrict__ Bs,
    const float* __restrict__ b2, const float* __restrict__ W3,
    const float* __restrict__ b3, float* __restrict__ out) {
  constexpr int K = N1_;   // 384
  constexpr int LDA = 40;
  __shared__ __align__(16) ushort sA[2][32 * LDA];
  __shared__ __align__(16) ushort sB[2][128 * LDA];
  __shared__ float pl[32][2];

  const int tid  = threadIdx.x;
  const int wid  = tid >> 6;
  const int lane = tid & 63;
  const int n0 = wid * 32;          // wave's 32-col slice of N2=128
  const int lrow = lane & 15;
  const int lk   = (lane >> 4) * 8;
  const int brow = blockIdx.x * 32;

  // A staging: 32 rows x 32 k by threads 0..127 (uint4 each)
  const int t7  = tid & 127;
  const int srA = t7 >> 2, skA = (t7 & 3) * 8;
  const ushort* pA = As + (size_t)(brow + srA) * K + skA;
  const int offA = srA * LDA + skA;
  // B staging: 128 rows x 32 k f16; each thread 2 uint4
  const int srB = tid >> 1, skB = (tid & 1) * 16;
  const ushort* pB = Bs + (size_t)srB * K + skB;
  const int offB = srB * LDA + skB;

  uint4 ra = {0, 0, 0, 0};
  if (tid < 128) ra = *(const uint4*)pA;
  uint4 rb0 = *(const uint4*)pB;
  uint4 rb1 = *(const uint4*)(pB + 8);
  if (tid < 128) *(uint4*)&sA[0][offA] = ra;
  *(uint4*)&sB[0][offB] = rb0;
  *(uint4*)&sB[0][offB + 8] = rb1;
  __syncthreads();

  f32x4 acc[2][2] = {};   // i: 2 row-frags (32 rows), j: 2 col-frags (32 cols)
  constexpr int NT = K / 32;  // 12

  for (int t = 0; t < NT; ++t) {
    const int cur = t & 1;
    if (t + 1 < NT) {
      if (tid < 128) ra = *(const uint4*)(pA + (size_t)(t + 1) * 32);
      rb0 = *(const uint4*)(pB + (size_t)(t + 1) * 32);
      rb1 = *(const uint4*)(pB + (size_t)(t + 1) * 32 + 8);
    }
    half8 av[2], bv[2];
    #pragma unroll
    for (int i = 0; i < 2; ++i)
      av[i] = *(const half8*)&sA[cur][(i * 16 + lrow) * LDA + lk];
    #pragma unroll
    for (int j = 0; j < 2; ++j)
      bv[j] = *(const half8*)&sB[cur][(n0 + j * 16 + lrow) * LDA + lk];
    #pragma unroll
    for (int i = 0; i < 2; ++i)
      #pragma unroll
      for (int j = 0; j < 2; ++j)
        acc[i][j] = __builtin_amdgcn_mfma_f32_16x16x32_f16(av[i], bv[j], acc[i][j], 0, 0, 0);
    if (t + 1 < NT) {
      __syncthreads();
      const int nxt = cur ^ 1;
      if (tid < 128) *(uint4*)&sA[nxt][offA] = ra;
      *(uint4*)&sB[nxt][offB] = rb0;
      *(uint4*)&sB[nxt][offB + 8] = rb1;
      __syncthreads();
    }
  }

  // ---- fused epilogue: h2 = relu(acc + b2); logits = h2 @ W3 + b3 ----
  __syncthreads();
  if (tid < 64) pl[tid >> 1][tid & 1] = 0.0f;
  float w3v[2][2], b2v[2];
  #pragma unroll
  for (int j = 0; j < 2; ++j) {
    const int col = n0 + j * 16 + lrow;
    w3v[j][0] = W3[col * 2 + 0];
    w3v[j][1] = W3[col * 2 + 1];
    b2v[j] = b2[col];
  }
  __syncthreads();
  #pragma unroll
  for (int i = 0; i < 2; ++i)
    #pragma unroll
    for (int r = 0; r < 4; ++r) {
      float p0 = 0.0f, p1 = 0.0f;
      #pragma unroll
      for (int j = 0; j < 2; ++j) {
        float v = fmaxf(acc[i][j][r] + b2v[j], 0.0f);
        p0 += v * w3v[j][0];
        p1 += v * w3v[j][1];
      }
      p0 += __shfl_xor(p0, 1); p1 += __shfl_xor(p1, 1);
      p0 += __shfl_xor(p0, 2); p1 += __shfl_xor(p1, 2);
      p0 += __shfl_xor(p0, 4); p1 += __shfl_xor(p1, 4);
      p0 += __shfl_xor(p0, 8); p1 += __shfl_xor(p1, 8);
      if (lrow == 0) {
        const int row = i * 16 + (lane >> 4) * 4 + r;
        atomicAdd(&pl[row][0], p0);
        atomicAdd(&pl[row][1], p1);
      }
    }
  __syncthreads();
  if (tid < 64) {
    const int row = tid >> 1, c = tid & 1;
    out[(size_t)(brow + row) * 2 + c] = pl[row][c] + b3[c];
  }
}

// ---------------------------------------------------------------------------
extern "C" void kernel_launch(void* const* d_in, const int* in_sizes, int n_in,
                              void* d_out, int out_size, void* d_ws, size_t ws_size,
                              hipStream_t stream) {
  const float* hidden  = (const float*)d_in[0];
  const int*   seg_ids = (const int*)d_in[1];
  const float* W1 = (const float*)d_in[2];
  const float* b1 = (const float*)d_in[3];
  const float* W2 = (const float*)d_in[4];
  const float* b2 = (const float*)d_in[5];
  const float* W3 = (const float*)d_in[6];
  const float* b3 = (const float*)d_in[7];
  float* out = (float*)d_out;

  // workspace layout (all 16B-aligned)
  char* p = (char*)d_ws;
  ushort* mh  = (ushort*)p;  p += (size_t)M_ * D_ * 2;     // means f16
  ushort* w1t = (ushort*)p;  p += (size_t)N1_ * D_ * 2;    // W1^T f16
  ushort* h1  = (ushort*)p;  p += (size_t)M_ * N1_ * 2;    // h1 f16
  ushort* w2t = (ushort*)p;  p += (size_t)N2_ * N1_ * 2;   // W2^T f16

  mean_prep_kernel<<<NMB + 288 + 48, 192, 0, stream>>>(
      hidden, seg_ids, mh, W1, w1t, W2, w2t);
  gemm_mfma8<<<dim3(N1_ / 64, M_ / 64), 512, 0, stream>>>(
      mh, w1t, b1, h1, M_, N1_, D_);
  gemm2_final<<<M_ / 32, 256, 0, stream>>>(
      h1, w2t, b2, W3, b3, out);
}